// Round 1
// baseline (1299.041 us; speedup 1.0000x reference)
//
#include <hip/hip_runtime.h>

#define NN 50000
#define NE 1250000
#define NG 256

// order-preserving float->uint encode for atomicMax on signed floats
static __device__ __forceinline__ unsigned enc_f32(float f) {
    unsigned b = __float_as_uint(f);
    return (b & 0x80000000u) ? ~b : (b | 0x80000000u);
}
static __device__ __forceinline__ float dec_f32(unsigned u) {
    unsigned b = (u & 0x80000000u) ? (u & 0x7fffffffu) : ~u;
    return __uint_as_float(b);
}

__global__ void k_init(unsigned* amax1, float* den1, unsigned* amax2, float* den2,
                       float* pooled, float* cnt) {
    int i = blockIdx.x * blockDim.x + threadIdx.x;
    if (i < NN) { amax1[i] = 0u; den1[i] = 0.f; amax2[i] = 0u; den2[i] = 0.f; }
    if (i < NG * 64) pooled[i] = 0.f;
    if (i < NG) cnt[i] = 0.f;
}

// One matrix per blockIdx.y (0=q,1=k,2=v,3=s). Weights staged in LDS (16KB).
// 4 nodes per iteration per block; thread = (node_sub, feat).
__global__ void k_linear(const float* __restrict__ xin, int relu_in,
                         const float* __restrict__ Wq, const float* __restrict__ bq,
                         const float* __restrict__ Wk, const float* __restrict__ bk,
                         const float* __restrict__ Wv, const float* __restrict__ bv,
                         const float* __restrict__ Ws, const float* __restrict__ bs,
                         float* __restrict__ q, float* __restrict__ k,
                         float* __restrict__ v, float* __restrict__ agg) {
    int mat = blockIdx.y;
    const float* W = mat == 0 ? Wq : mat == 1 ? Wk : mat == 2 ? Wv : Ws;
    const float* b = mat == 0 ? bq : mat == 1 ? bk : mat == 2 ? bv : bs;
    float* outp    = mat == 0 ? q  : mat == 1 ? k  : mat == 2 ? v  : agg;

    __shared__ float sW[64][64];
    __shared__ float sx[4][64];
    for (int i = threadIdx.x; i < 4096; i += 256) sW[i >> 6][i & 63] = W[i];

    int feat = threadIdx.x & 63;
    int sub  = threadIdx.x >> 6;
    float bias = b[feat];

    for (int n0 = blockIdx.x * 4; n0 < NN; n0 += gridDim.x * 4) {
        __syncthreads();
        int nn = n0 + sub;
        if (nn < NN) {
            float xv = xin[nn * 64 + feat];
            sx[sub][feat] = relu_in ? fmaxf(xv, 0.f) : xv;
        }
        __syncthreads();
        if (nn < NN) {
            float acc = bias;
            #pragma unroll
            for (int kk = 0; kk < 64; kk++) acc += sx[sub][kk] * sW[kk][feat];
            outp[nn * 64 + feat] = acc;
        }
    }
}

// one thread per edge: alpha = dot(q[dst], k[src] + ew*We) / 8; atomicMax amax[dst]
__global__ void k_alpha(const int* __restrict__ src, const int* __restrict__ dst,
                        const float* __restrict__ ew,
                        const float* __restrict__ q, const float* __restrict__ kf,
                        const float* __restrict__ We,
                        float* __restrict__ alpha, unsigned* __restrict__ amax) {
    __shared__ float sWe[64];
    if (threadIdx.x < 64) sWe[threadIdx.x] = We[threadIdx.x];
    __syncthreads();
    int e = blockIdx.x * 256 + threadIdx.x;
    if (e >= NE) return;
    int s = src[e], d = dst[e];
    float w = ew[e];
    const float4* qr = (const float4*)(q + d * 64);
    const float4* kr = (const float4*)(kf + s * 64);
    const float4* wr = (const float4*)sWe;
    float acc = 0.f;
    #pragma unroll
    for (int i = 0; i < 16; i++) {
        float4 qv = qr[i], kv = kr[i], wv = wr[i];
        acc += qv.x * fmaf(w, wv.x, kv.x);
        acc += qv.y * fmaf(w, wv.y, kv.y);
        acc += qv.z * fmaf(w, wv.z, kv.z);
        acc += qv.w * fmaf(w, wv.w, kv.w);
    }
    acc *= 0.125f;
    alpha[e] = acc;
    atomicMax(amax + d, enc_f32(acc));
}

// one thread per edge: denom[dst] += exp(alpha - amax[dst])
__global__ void k_denom(const int* __restrict__ dst, const float* __restrict__ alpha,
                        const unsigned* __restrict__ amax, float* __restrict__ den) {
    int e = blockIdx.x * 256 + threadIdx.x;
    if (e >= NE) return;
    int d = dst[e];
    float m = dec_f32(amax[d]);
    atomicAdd(den + d, __expf(alpha[e] - m));
}

// one wave (64 lanes) per edge, lane = feature:
// agg[dst] += w * (v[src] + ew*We),  w = exp(alpha - amax[dst]) / denom[dst]
__global__ void k_agg(const int* __restrict__ src, const int* __restrict__ dst,
                      const float* __restrict__ ew, const float* __restrict__ alpha,
                      const unsigned* __restrict__ amax, const float* __restrict__ den,
                      const float* __restrict__ v, const float* __restrict__ We,
                      float* __restrict__ agg) {
    long gid = (long)blockIdx.x * 256 + threadIdx.x;
    int e = (int)(gid >> 6);
    int lane = threadIdx.x & 63;
    if (e >= NE) return;
    int s = src[e], d = dst[e];
    float m = dec_f32(amax[d]);
    float w = __expf(alpha[e] - m) / fmaxf(den[d], 1e-16f);
    float ev = ew[e] * We[lane];
    atomicAdd(agg + d * 64 + lane, w * (v[s * 64 + lane] + ev));
}

// wave per node: pooled[batch[n]] += relu(h[n]); cnt[batch[n]] += 1
__global__ void k_pool(const float* __restrict__ h, const int* __restrict__ batch,
                       float* __restrict__ pooled, float* __restrict__ cnt) {
    long gid = (long)blockIdx.x * 256 + threadIdx.x;
    int n = (int)(gid >> 6);
    int lane = threadIdx.x & 63;
    if (n >= NN) return;
    int g = batch[n];
    atomicAdd(pooled + g * 64 + lane, fmaxf(h[n * 64 + lane], 0.f));
    if (lane == 0) atomicAdd(cnt + g, 1.f);
}

// 256 graphs x 2 outputs
__global__ void k_final(const float* __restrict__ pooled, const float* __restrict__ cnt,
                        const float* __restrict__ Wl, const float* __restrict__ bl,
                        float* __restrict__ out) {
    int g = blockIdx.x * blockDim.x + threadIdx.x;
    if (g >= NG) return;
    float c = fmaxf(cnt[g], 1.0f);
    float inv = 1.0f / c;
    float a0 = 0.f, a1 = 0.f;
    for (int f = 0; f < 64; f++) {
        float p = pooled[g * 64 + f] * inv;
        a0 += p * Wl[f * 2 + 0];
        a1 += p * Wl[f * 2 + 1];
    }
    out[g * 2 + 0] = a0 + bl[0];
    out[g * 2 + 1] = a1 + bl[1];
}

extern "C" void kernel_launch(void* const* d_in, const int* in_sizes, int n_in,
                              void* d_out, int out_size, void* d_ws, size_t ws_size,
                              hipStream_t stream) {
    const float* x    = (const float*)d_in[0];
    const int*   ei   = (const int*)d_in[1];
    const float* ew   = (const float*)d_in[2];
    const int*   batch= (const int*)d_in[3];
    const float *Wq1 = (const float*)d_in[4],  *bq1 = (const float*)d_in[5],
                *Wk1 = (const float*)d_in[6],  *bk1 = (const float*)d_in[7],
                *Wv1 = (const float*)d_in[8],  *bv1 = (const float*)d_in[9],
                *We1 = (const float*)d_in[10], *Ws1 = (const float*)d_in[11],
                *bs1 = (const float*)d_in[12],
                *Wq2 = (const float*)d_in[13], *bq2 = (const float*)d_in[14],
                *Wk2 = (const float*)d_in[15], *bk2 = (const float*)d_in[16],
                *Wv2 = (const float*)d_in[17], *bv2 = (const float*)d_in[18],
                *We2 = (const float*)d_in[19], *Ws2 = (const float*)d_in[20],
                *bs2 = (const float*)d_in[21],
                *Wl  = (const float*)d_in[22], *bl  = (const float*)d_in[23];
    const int* src = ei;        // edge_index[0]
    const int* dst = ei + NE;   // edge_index[1]
    float* out = (float*)d_out;

    float* p = (float*)d_ws;
    float* q     = p; p += NN * 64;
    float* kf    = p; p += NN * 64;
    float* vf    = p; p += NN * 64;
    float* agg1  = p; p += NN * 64;
    float* agg2  = p; p += NN * 64;
    float* alpha = p; p += NE;
    float* den1  = p; p += NN;
    float* den2  = p; p += NN;
    float* pooled= p; p += NG * 64;
    float* cnt   = p; p += NG;
    unsigned* amax1 = (unsigned*)p; p += NN;
    unsigned* amax2 = (unsigned*)p; p += NN;

    dim3 b256(256);
    k_init<<<dim3((NN + 255) / 256), b256, 0, stream>>>(amax1, den1, amax2, den2, pooled, cnt);

    dim3 lgrid(512, 4);
    int egrid = (NE + 255) / 256;        // thread per edge
    int agrid = (int)(((long)NE * 64 + 255) / 256);  // wave per edge

    // ---- layer 1 ----
    k_linear<<<lgrid, b256, 0, stream>>>(x, 0, Wq1, bq1, Wk1, bk1, Wv1, bv1, Ws1, bs1,
                                         q, kf, vf, agg1);
    k_alpha<<<egrid, b256, 0, stream>>>(src, dst, ew, q, kf, We1, alpha, amax1);
    k_denom<<<egrid, b256, 0, stream>>>(dst, alpha, amax1, den1);
    k_agg<<<agrid, b256, 0, stream>>>(src, dst, ew, alpha, amax1, den1, vf, We1, agg1);

    // ---- layer 2 (input = relu(agg1), applied on read) ----
    k_linear<<<lgrid, b256, 0, stream>>>(agg1, 1, Wq2, bq2, Wk2, bk2, Wv2, bv2, Ws2, bs2,
                                         q, kf, vf, agg2);
    k_alpha<<<egrid, b256, 0, stream>>>(src, dst, ew, q, kf, We2, alpha, amax2);
    k_denom<<<egrid, b256, 0, stream>>>(dst, alpha, amax2, den2);
    k_agg<<<agrid, b256, 0, stream>>>(src, dst, ew, alpha, amax2, den2, vf, We2, agg2);

    // ---- pool + head (relu applied on read of agg2) ----
    k_pool<<<dim3((int)(((long)NN * 64 + 255) / 256)), b256, 0, stream>>>(agg2, batch, pooled, cnt);
    k_final<<<dim3(1), b256, 0, stream>>>(pooled, cnt, Wl, bl, out);
}

// Round 2
// 802.818 us; speedup vs baseline: 1.6181x; 1.6181x over previous
//
#include <hip/hip_runtime.h>

#define NN 50000
#define NE 1250000
#define NG 256
#define NB 196   // ceil(NN/256)

// ---------- init ----------
__global__ void k_zero(int* deg, float* pooled, float* cnt) {
    int i = blockIdx.x * 256 + threadIdx.x;
    if (i < NN) deg[i] = 0;
    if (i < NG * 64) pooled[i] = 0.f;
    if (i < NG) cnt[i] = 0.f;
}

// ---------- CSR build: histogram, scan, scatter ----------
__global__ void k_hist(const int* __restrict__ dst, int* __restrict__ deg) {
    int e = blockIdx.x * 256 + threadIdx.x;
    if (e >= NE) return;
    atomicAdd(deg + dst[e], 1);
}

__global__ void k_scanp(const int* __restrict__ deg, int* __restrict__ psum) {
    __shared__ int s[256];
    int t = threadIdx.x, i = blockIdx.x * 256 + t;
    s[t] = (i < NN) ? deg[i] : 0;
    __syncthreads();
    for (int o = 128; o; o >>= 1) {
        if (t < o) s[t] += s[t + o];
        __syncthreads();
    }
    if (t == 0) psum[blockIdx.x] = s[0];
}

__global__ void k_scanb(const int* __restrict__ psum, int* __restrict__ base) {
    __shared__ int s[256];
    int t = threadIdx.x;
    int v = (t < NB) ? psum[t] : 0;
    s[t] = v;
    __syncthreads();
    for (int o = 1; o < 256; o <<= 1) {
        int tmp = (t >= o) ? s[t - o] : 0;
        __syncthreads();
        s[t] += tmp;
        __syncthreads();
    }
    base[t] = s[t] - v;  // exclusive
}

__global__ void k_scanf(const int* __restrict__ deg, const int* __restrict__ base,
                        int* __restrict__ off, int* __restrict__ cursor) {
    __shared__ int s[256];
    int t = threadIdx.x, i = blockIdx.x * 256 + t;
    int v = (i < NN) ? deg[i] : 0;
    s[t] = v;
    __syncthreads();
    for (int o = 1; o < 256; o <<= 1) {
        int tmp = (t >= o) ? s[t - o] : 0;
        __syncthreads();
        s[t] += tmp;
        __syncthreads();
    }
    if (i < NN) {
        int e = base[blockIdx.x] + s[t] - v;
        off[i] = e;
        cursor[i] = e;
    }
}

__global__ void k_scatter(const int* __restrict__ src, const int* __restrict__ dst,
                          const float* __restrict__ ew, int* __restrict__ cursor,
                          int* __restrict__ srcP, float* __restrict__ ewP) {
    int e = blockIdx.x * 256 + threadIdx.x;
    if (e >= NE) return;
    int d = dst[e];
    int pos = atomicAdd(cursor + d, 1);
    srcP[pos] = src[e];
    ewP[pos] = ew[e];
}

// ---------- node linear: q, interleaved k|v, agg = x@Ws+bs ----------
// blockIdx.y: 0=q,1=k,2=v,3=s. Weights staged in LDS.
__global__ void k_linear(const float* __restrict__ xin, int relu_in,
                         const float* __restrict__ Wq, const float* __restrict__ bq,
                         const float* __restrict__ Wk, const float* __restrict__ bk,
                         const float* __restrict__ Wv, const float* __restrict__ bv,
                         const float* __restrict__ Ws, const float* __restrict__ bs,
                         float* __restrict__ q, float* __restrict__ kv,
                         float* __restrict__ agg) {
    int mat = blockIdx.y;
    const float* W = mat == 0 ? Wq : mat == 1 ? Wk : mat == 2 ? Wv : Ws;
    const float* b = mat == 0 ? bq : mat == 1 ? bk : mat == 2 ? bv : bs;

    __shared__ float sW[64][64];
    __shared__ float sx[4][64];
    for (int i = threadIdx.x; i < 4096; i += 256) sW[i >> 6][i & 63] = W[i];

    int feat = threadIdx.x & 63;
    int sub  = threadIdx.x >> 6;
    float bias = b[feat];

    for (int n0 = blockIdx.x * 4; n0 < NN; n0 += gridDim.x * 4) {
        __syncthreads();
        int nn = n0 + sub;
        if (nn < NN) {
            float xv = xin[nn * 64 + feat];
            sx[sub][feat] = relu_in ? fmaxf(xv, 0.f) : xv;
        }
        __syncthreads();
        if (nn < NN) {
            float acc = bias;
            #pragma unroll
            for (int kk = 0; kk < 64; kk++) acc += sx[sub][kk] * sW[kk][feat];
            if (mat == 0)      q[nn * 64 + feat] = acc;
            else if (mat == 1) kv[nn * 128 + feat] = acc;
            else if (mat == 2) kv[nn * 128 + 64 + feat] = acc;
            else               agg[nn * 64 + feat] = acc;
        }
    }
}

// ---------- fused edge kernel: one wave per dst node, online softmax ----------
__global__ void k_edge(const int* __restrict__ srcP, const float* __restrict__ ewP,
                       const int* __restrict__ off, const int* __restrict__ deg,
                       const float* __restrict__ q, const float* __restrict__ kv,
                       const float* __restrict__ We, float* __restrict__ agg) {
    long gid = (long)blockIdx.x * 256 + threadIdx.x;
    int n = (int)(gid >> 6);
    int lane = threadIdx.x & 63;
    if (n >= NN) return;

    float qv = q[n * 64 + lane];
    float wev = We[lane];
    int st = off[n], dg = deg[n];

    float m = -INFINITY, den = 0.f, acc = 0.f;
    for (int j = st; j < st + dg; ++j) {
        int s = srcP[j];
        float w = ewP[j];
        float kvx = kv[s * 128 + lane];
        float vvx = kv[s * 128 + 64 + lane];
        float t = qv * fmaf(w, wev, kvx);
        #pragma unroll
        for (int o = 32; o; o >>= 1) t += __shfl_xor(t, o);
        t *= 0.125f;
        float nm = fmaxf(m, t);
        float sc = __expf(m - nm);
        float p  = __expf(t - nm);
        den = den * sc + p;
        acc = acc * sc + p * fmaf(w, wev, vvx);
        m = nm;
    }
    agg[n * 64 + lane] += acc / fmaxf(den, 1e-16f);
}

// ---------- pool + head ----------
__global__ void k_pool(const float* __restrict__ h, const int* __restrict__ batch,
                       float* __restrict__ pooled, float* __restrict__ cnt) {
    long gid = (long)blockIdx.x * 256 + threadIdx.x;
    int n = (int)(gid >> 6);
    int lane = threadIdx.x & 63;
    if (n >= NN) return;
    int g = batch[n];
    atomicAdd(pooled + g * 64 + lane, fmaxf(h[n * 64 + lane], 0.f));
    if (lane == 0) atomicAdd(cnt + g, 1.f);
}

__global__ void k_final(const float* __restrict__ pooled, const float* __restrict__ cnt,
                        const float* __restrict__ Wl, const float* __restrict__ bl,
                        float* __restrict__ out) {
    int g = blockIdx.x * blockDim.x + threadIdx.x;
    if (g >= NG) return;
    float c = fmaxf(cnt[g], 1.0f);
    float inv = 1.0f / c;
    float a0 = 0.f, a1 = 0.f;
    for (int f = 0; f < 64; f++) {
        float p = pooled[g * 64 + f] * inv;
        a0 += p * Wl[f * 2 + 0];
        a1 += p * Wl[f * 2 + 1];
    }
    out[g * 2 + 0] = a0 + bl[0];
    out[g * 2 + 1] = a1 + bl[1];
}

extern "C" void kernel_launch(void* const* d_in, const int* in_sizes, int n_in,
                              void* d_out, int out_size, void* d_ws, size_t ws_size,
                              hipStream_t stream) {
    const float* x    = (const float*)d_in[0];
    const int*   ei   = (const int*)d_in[1];
    const float* ew   = (const float*)d_in[2];
    const int*   batch= (const int*)d_in[3];
    const float *Wq1 = (const float*)d_in[4],  *bq1 = (const float*)d_in[5],
                *Wk1 = (const float*)d_in[6],  *bk1 = (const float*)d_in[7],
                *Wv1 = (const float*)d_in[8],  *bv1 = (const float*)d_in[9],
                *We1 = (const float*)d_in[10], *Ws1 = (const float*)d_in[11],
                *bs1 = (const float*)d_in[12],
                *Wq2 = (const float*)d_in[13], *bq2 = (const float*)d_in[14],
                *Wk2 = (const float*)d_in[15], *bk2 = (const float*)d_in[16],
                *Wv2 = (const float*)d_in[17], *bv2 = (const float*)d_in[18],
                *We2 = (const float*)d_in[19], *Ws2 = (const float*)d_in[20],
                *bs2 = (const float*)d_in[21],
                *Wl  = (const float*)d_in[22], *bl  = (const float*)d_in[23];
    const int* src = ei;        // edge_index[0]
    const int* dst = ei + NE;   // edge_index[1]
    float* out = (float*)d_out;

    float* p = (float*)d_ws;
    float* q      = p; p += NN * 64;
    float* kv     = p; p += NN * 128;
    float* agg1   = p; p += NN * 64;
    float* agg2   = p; p += NN * 64;
    float* ewP    = p; p += NE;
    float* pooled = p; p += NG * 64;
    float* cnt    = p; p += NG;
    int* ip = (int*)p;
    int* srcP   = ip; ip += NE;
    int* deg    = ip; ip += NN;
    int* off    = ip; ip += NN;
    int* cursor = ip; ip += NN;
    int* psum   = ip; ip += 256;
    int* base   = ip; ip += 256;

    dim3 b256(256);
    int ngrid = (NN + 255) / 256;                       // 196
    int egrid = (NE + 255) / 256;                       // 4883
    int wgrid = (int)(((long)NN * 64 + 255) / 256);     // wave per node

    // ---- CSR build (once, shared by both layers) ----
    k_zero<<<ngrid, b256, 0, stream>>>(deg, pooled, cnt);
    k_hist<<<egrid, b256, 0, stream>>>(dst, deg);
    k_scanp<<<NB, b256, 0, stream>>>(deg, psum);
    k_scanb<<<1, b256, 0, stream>>>(psum, base);
    k_scanf<<<NB, b256, 0, stream>>>(deg, base, off, cursor);
    k_scatter<<<egrid, b256, 0, stream>>>(src, dst, ew, cursor, srcP, ewP);

    dim3 lgrid(512, 4);

    // ---- layer 1 ----
    k_linear<<<lgrid, b256, 0, stream>>>(x, 0, Wq1, bq1, Wk1, bk1, Wv1, bv1, Ws1, bs1,
                                         q, kv, agg1);
    k_edge<<<wgrid, b256, 0, stream>>>(srcP, ewP, off, deg, q, kv, We1, agg1);

    // ---- layer 2 (input = relu(agg1), applied on read) ----
    k_linear<<<lgrid, b256, 0, stream>>>(agg1, 1, Wq2, bq2, Wk2, bk2, Wv2, bv2, Ws2, bs2,
                                         q, kv, agg2);
    k_edge<<<wgrid, b256, 0, stream>>>(srcP, ewP, off, deg, q, kv, We2, agg2);

    // ---- pool + head (relu applied on read of agg2) ----
    k_pool<<<wgrid, b256, 0, stream>>>(agg2, batch, pooled, cnt);
    k_final<<<1, b256, 0, stream>>>(pooled, cnt, Wl, bl, out);
}

// Round 3
// 451.198 us; speedup vs baseline: 2.8791x; 1.7793x over previous
//
#include <hip/hip_runtime.h>

#define NN 50000
#define NE 1250000
#define NG 256
#define NB 196   // ceil(NN/256)

// ---------- init ----------
__global__ void k_zero(int* deg) {
    int i = blockIdx.x * 256 + threadIdx.x;
    if (i < NN) deg[i] = 0;
}

// ---------- CSR build ----------
__global__ void k_hist(const int* __restrict__ dst, int* __restrict__ deg) {
    int e = blockIdx.x * 256 + threadIdx.x;
    if (e < NE) atomicAdd(deg + dst[e], 1);
}

__global__ void k_scanp(const int* __restrict__ deg, int* __restrict__ psum) {
    __shared__ int s[256];
    int t = threadIdx.x, i = blockIdx.x * 256 + t;
    s[t] = (i < NN) ? deg[i] : 0;
    __syncthreads();
    for (int o = 128; o; o >>= 1) {
        if (t < o) s[t] += s[t + o];
        __syncthreads();
    }
    if (t == 0) psum[blockIdx.x] = s[0];
}

__global__ void k_scanb(const int* __restrict__ psum, int* __restrict__ base) {
    __shared__ int s[256];
    int t = threadIdx.x;
    int v = (t < NB) ? psum[t] : 0;
    s[t] = v;
    __syncthreads();
    for (int o = 1; o < 256; o <<= 1) {
        int tmp = (t >= o) ? s[t - o] : 0;
        __syncthreads();
        s[t] += tmp;
        __syncthreads();
    }
    base[t] = s[t] - v;  // exclusive
}

__global__ void k_scanf(const int* __restrict__ deg, const int* __restrict__ base,
                        int* __restrict__ off, int* __restrict__ cursor) {
    __shared__ int s[256];
    int t = threadIdx.x, i = blockIdx.x * 256 + t;
    int v = (i < NN) ? deg[i] : 0;
    s[t] = v;
    __syncthreads();
    for (int o = 1; o < 256; o <<= 1) {
        int tmp = (t >= o) ? s[t - o] : 0;
        __syncthreads();
        s[t] += tmp;
        __syncthreads();
    }
    if (i < NN) {
        int e = base[blockIdx.x] + s[t] - v;
        off[i] = e;
        cursor[i] = e;
    }
}

__global__ void k_scatter(const int* __restrict__ src, const int* __restrict__ dst,
                          const float* __restrict__ ew, int* __restrict__ cursor,
                          int2* __restrict__ pairP) {
    int e = blockIdx.x * 256 + threadIdx.x;
    if (e >= NE) return;
    int d = dst[e];
    int pos = atomicAdd(cursor + d, 1);
    pairP[pos] = make_int2(src[e], __float_as_int(ew[e]));
}

// ---------- fused node linear: wave = matrix (0=q,1=k,2=v,3=s), W column in regs ----------
__global__ void k_linear(const float* __restrict__ xin, int relu_in,
                         const float* __restrict__ Wq, const float* __restrict__ bq,
                         const float* __restrict__ Wk, const float* __restrict__ bk,
                         const float* __restrict__ Wv, const float* __restrict__ bv,
                         const float* __restrict__ Ws, const float* __restrict__ bs,
                         float* __restrict__ q, float* __restrict__ kv,
                         float* __restrict__ agg) {
    int tid = threadIdx.x;
    int mat = tid >> 6, feat = tid & 63;
    const float* W = mat == 0 ? Wq : mat == 1 ? Wk : mat == 2 ? Wv : Ws;
    const float* b = mat == 0 ? bq : mat == 1 ? bk : mat == 2 ? bv : bs;

    float wcol[64];
    #pragma unroll
    for (int kk = 0; kk < 64; kk++) wcol[kk] = W[kk * 64 + feat];
    float bias = b[feat];

    __shared__ float sx[16 * 64];
    const float4* x4 = (const float4*)xin;

    for (int n0 = blockIdx.x * 16; n0 < NN; n0 += gridDim.x * 16) {
        __syncthreads();
        float4 xv = x4[n0 * 16 + tid];   // 256 threads x float4 = 16 nodes
        if (relu_in) {
            xv.x = fmaxf(xv.x, 0.f); xv.y = fmaxf(xv.y, 0.f);
            xv.z = fmaxf(xv.z, 0.f); xv.w = fmaxf(xv.w, 0.f);
        }
        ((float4*)sx)[tid] = xv;
        __syncthreads();
        for (int c = 0; c < 16; c++) {
            const float4* sxc = (const float4*)(sx + c * 64);
            float acc = bias;
            #pragma unroll
            for (int k4 = 0; k4 < 16; k4++) {
                float4 v = sxc[k4];
                acc = fmaf(v.x, wcol[4 * k4 + 0], acc);
                acc = fmaf(v.y, wcol[4 * k4 + 1], acc);
                acc = fmaf(v.z, wcol[4 * k4 + 2], acc);
                acc = fmaf(v.w, wcol[4 * k4 + 3], acc);
            }
            int nn = n0 + c;
            if (mat == 0)      q[nn * 64 + feat] = acc;
            else if (mat == 1) kv[nn * 128 + feat] = acc;
            else if (mat == 2) kv[nn * 128 + 64 + feat] = acc;
            else               agg[nn * 64 + feat] = acc;
        }
    }
}

// ---------- fused edge kernel: wave per dst node, 4 edges in flight (16-lane groups) ----------
__global__ void k_edge(const int2* __restrict__ pairP,
                       const int* __restrict__ off, const int* __restrict__ deg,
                       const float* __restrict__ q, const float* __restrict__ kv,
                       const float* __restrict__ We, float* __restrict__ agg) {
    long gid = (long)blockIdx.x * 256 + threadIdx.x;
    int n = (int)(gid >> 6);
    if (n >= NN) return;
    int lane = threadIdx.x & 63;
    int g = lane >> 4, l = lane & 15;

    const float4* q4  = (const float4*)q;
    const float4* kv4 = (const float4*)kv;
    const float4* We4 = (const float4*)We;
    float4 qv  = q4[n * 16 + l];
    float4 wev = We4[l];
    int st = off[n], dg = deg[n];
    int nit = (dg + 3) >> 2;

    float m = -INFINITY, den = 0.f;
    float4 acc = make_float4(0.f, 0.f, 0.f, 0.f);

    // 2-deep software pipeline per 16-lane group
    bool vaA = (g < dg), vaB = (4 + g < dg);
    int2 prA = make_int2(0, 0), prB = make_int2(0, 0);
    float4 kA = make_float4(0,0,0,0), vA = kA, kB = kA, vB = kA;
    if (vaA) prA = pairP[st + g];
    if (vaB) prB = pairP[st + 4 + g];
    if (vaA) { kA = kv4[prA.x * 32 + l]; vA = kv4[prA.x * 32 + 16 + l]; }

    for (int i = 0; i < nit; i++) {
        bool vaC = (4 * (i + 2) + g < dg);
        int2 prC = make_int2(0, 0);
        if (vaC) prC = pairP[st + 4 * (i + 2) + g];
        if (vaB) { kB = kv4[prB.x * 32 + l]; vB = kv4[prB.x * 32 + 16 + l]; }
        if (vaA) {
            float w = __int_as_float(prA.y);
            float t =            qv.x * fmaf(w, wev.x, kA.x);
            t = fmaf(qv.y, fmaf(w, wev.y, kA.y), t);
            t = fmaf(qv.z, fmaf(w, wev.z, kA.z), t);
            t = fmaf(qv.w, fmaf(w, wev.w, kA.w), t);
            t += __shfl_xor(t, 1); t += __shfl_xor(t, 2);
            t += __shfl_xor(t, 4); t += __shfl_xor(t, 8);
            t *= 0.125f;
            float nm = fmaxf(m, t);
            float sc = __expf(m - nm);   // m=-inf,t finite -> 0, no NaN
            float p  = __expf(t - nm);
            den = den * sc + p;
            acc.x = fmaf(p, fmaf(w, wev.x, vA.x), acc.x * sc);
            acc.y = fmaf(p, fmaf(w, wev.y, vA.y), acc.y * sc);
            acc.z = fmaf(p, fmaf(w, wev.z, vA.z), acc.z * sc);
            acc.w = fmaf(p, fmaf(w, wev.w, vA.w), acc.w * sc);
            m = nm;
        }
        vaA = vaB; prA = prB; kA = kB; vA = vB;
        vaB = vaC; prB = prC;
    }

    // merge the 4 group softmax states (xor 16, then 32)
    #pragma unroll
    for (int o = 16; o <= 32; o <<= 1) {
        float  om   = __shfl_xor(m, o);
        float  oden = __shfl_xor(den, o);
        float4 oacc;
        oacc.x = __shfl_xor(acc.x, o); oacc.y = __shfl_xor(acc.y, o);
        oacc.z = __shfl_xor(acc.z, o); oacc.w = __shfl_xor(acc.w, o);
        float nm = fmaxf(m, om);
        float s1 = __expf(fmaxf(m - nm, -80.f));   // NaN-guard for -inf - -inf
        float s2 = __expf(fmaxf(om - nm, -80.f));
        den = den * s1 + oden * s2;
        acc.x = acc.x * s1 + oacc.x * s2;
        acc.y = acc.y * s1 + oacc.y * s2;
        acc.z = acc.z * s1 + oacc.z * s2;
        acc.w = acc.w * s1 + oacc.w * s2;
        m = nm;
    }

    if (g == 0) {
        float inv = 1.f / fmaxf(den, 1e-16f);
        float4* agg4 = (float4*)agg;
        float4 a = agg4[n * 16 + l];
        a.x = fmaf(acc.x, inv, a.x);
        a.y = fmaf(acc.y, inv, a.y);
        a.z = fmaf(acc.z, inv, a.z);
        a.w = fmaf(acc.w, inv, a.w);
        agg4[n * 16 + l] = a;
    }
}

// ---------- pool + head: block per graph, batch is sorted ----------
__global__ void k_final(const float* __restrict__ h, const int* __restrict__ batch,
                        const float* __restrict__ Wl, const float* __restrict__ bl,
                        float* __restrict__ out) {
    int g = blockIdx.x;
    int tid = threadIdx.x;
    int lo = 0, hi = NN;
    while (lo < hi) { int mid = (lo + hi) >> 1; if (batch[mid] < g) lo = mid + 1; else hi = mid; }
    int s0 = lo;
    hi = NN;
    while (lo < hi) { int mid = (lo + hi) >> 1; if (batch[mid] < g + 1) lo = mid + 1; else hi = mid; }
    int s1 = lo;

    int sub = tid >> 6, lane = tid & 63;
    float a = 0.f;
    for (int n = s0 + sub; n < s1; n += 4) a += fmaxf(h[n * 64 + lane], 0.f);
    __shared__ float sred[4][64];
    sred[sub][lane] = a;
    __syncthreads();
    if (tid < 64) {
        float p = (sred[0][tid] + sred[1][tid] + sred[2][tid] + sred[3][tid])
                  / fmaxf((float)(s1 - s0), 1.f);
        float a0 = p * Wl[tid * 2 + 0];
        float a1 = p * Wl[tid * 2 + 1];
        #pragma unroll
        for (int o = 1; o < 64; o <<= 1) { a0 += __shfl_xor(a0, o); a1 += __shfl_xor(a1, o); }
        if (tid == 0) { out[g * 2 + 0] = a0 + bl[0]; out[g * 2 + 1] = a1 + bl[1]; }
    }
}

extern "C" void kernel_launch(void* const* d_in, const int* in_sizes, int n_in,
                              void* d_out, int out_size, void* d_ws, size_t ws_size,
                              hipStream_t stream) {
    const float* x    = (const float*)d_in[0];
    const int*   ei   = (const int*)d_in[1];
    const float* ew   = (const float*)d_in[2];
    const int*   batch= (const int*)d_in[3];
    const float *Wq1 = (const float*)d_in[4],  *bq1 = (const float*)d_in[5],
                *Wk1 = (const float*)d_in[6],  *bk1 = (const float*)d_in[7],
                *Wv1 = (const float*)d_in[8],  *bv1 = (const float*)d_in[9],
                *We1 = (const float*)d_in[10], *Ws1 = (const float*)d_in[11],
                *bs1 = (const float*)d_in[12],
                *Wq2 = (const float*)d_in[13], *bq2 = (const float*)d_in[14],
                *Wk2 = (const float*)d_in[15], *bk2 = (const float*)d_in[16],
                *Wv2 = (const float*)d_in[17], *bv2 = (const float*)d_in[18],
                *We2 = (const float*)d_in[19], *Ws2 = (const float*)d_in[20],
                *bs2 = (const float*)d_in[21],
                *Wl  = (const float*)d_in[22], *bl  = (const float*)d_in[23];
    const int* src = ei;        // edge_index[0]
    const int* dst = ei + NE;   // edge_index[1]
    float* out = (float*)d_out;

    float* p = (float*)d_ws;
    float* q    = p; p += (size_t)NN * 64;
    float* kv   = p; p += (size_t)NN * 128;
    float* agg1 = p; p += (size_t)NN * 64;
    float* agg2 = p; p += (size_t)NN * 64;
    int2* pairP = (int2*)p; 
    int* ip = (int*)(pairP + NE);
    int* deg    = ip; ip += NN;
    int* off    = ip; ip += NN;
    int* cursor = ip; ip += NN;
    int* psum   = ip; ip += 256;
    int* base   = ip; ip += 256;

    dim3 b256(256);
    int ngrid = (NN + 255) / 256;                       // 196
    int egrid = (NE + 255) / 256;                       // 4883
    int wgrid = (int)(((long)NN * 64 + 255) / 256);     // wave per node: 12500

    // ---- CSR build (once, shared by both layers) ----
    k_zero<<<ngrid, b256, 0, stream>>>(deg);
    k_hist<<<egrid, b256, 0, stream>>>(dst, deg);
    k_scanp<<<NB, b256, 0, stream>>>(deg, psum);
    k_scanb<<<1, b256, 0, stream>>>(psum, base);
    k_scanf<<<NB, b256, 0, stream>>>(deg, base, off, cursor);
    k_scatter<<<egrid, b256, 0, stream>>>(src, dst, ew, cursor, pairP);

    // ---- layer 1 ----
    k_linear<<<512, b256, 0, stream>>>(x, 0, Wq1, bq1, Wk1, bk1, Wv1, bv1, Ws1, bs1,
                                       q, kv, agg1);
    k_edge<<<wgrid, b256, 0, stream>>>(pairP, off, deg, q, kv, We1, agg1);

    // ---- layer 2 (input = relu(agg1), applied on read) ----
    k_linear<<<512, b256, 0, stream>>>(agg1, 1, Wq2, bq2, Wk2, bk2, Wv2, bv2, Ws2, bs2,
                                       q, kv, agg2);
    k_edge<<<wgrid, b256, 0, stream>>>(pairP, off, deg, q, kv, We2, agg2);

    // ---- pool + head (relu applied on read of agg2) ----
    k_final<<<NG, b256, 0, stream>>>(agg2, batch, Wl, bl, out);
}

// Round 4
// 328.847 us; speedup vs baseline: 3.9503x; 1.3721x over previous
//
#include <hip/hip_runtime.h>
#include <hip/hip_fp16.h>

#define NN 50000
#define NE 1250000
#define NG 256
#define NBKT 782          // ceil(NN/64) buckets of 64 nodes
#define TILE 2048         // edges per multisplit block
#define NTB 611           // ceil(NE/TILE)

// ---------- zero bucket counters ----------
__global__ void k_zero(int* bcnt) {
    int i = blockIdx.x * 256 + threadIdx.x;
    if (i < NBKT) bcnt[i] = 0;
}

// ---------- phase 1a: bucket histogram ----------
__global__ void k_bcount(const int* __restrict__ dst, int* __restrict__ bcnt) {
    __shared__ int cnt[NBKT];
    for (int i = threadIdx.x; i < NBKT; i += 256) cnt[i] = 0;
    __syncthreads();
    int e0 = blockIdx.x * TILE;
    #pragma unroll
    for (int j = 0; j < 8; j++) {
        int e = e0 + j * 256 + threadIdx.x;
        if (e < NE) atomicAdd(&cnt[dst[e] >> 6], 1);
    }
    __syncthreads();
    for (int i = threadIdx.x; i < NBKT; i += 256)
        if (cnt[i]) atomicAdd(&bcnt[i], cnt[i]);
}

// ---------- phase 1b: scan bucket counts -> bases ----------
__global__ void k_bscan(const int* __restrict__ bcnt, int* __restrict__ bstart,
                        int* __restrict__ gCursor) {
    __shared__ int s[256];
    int t = threadIdx.x;
    int c[4]; int sum = 0;
    #pragma unroll
    for (int j = 0; j < 4; j++) {
        int b = t * 4 + j;
        c[j] = (b < NBKT) ? bcnt[b] : 0;
        sum += c[j];
    }
    s[t] = sum;
    __syncthreads();
    for (int o = 1; o < 256; o <<= 1) {
        int tmp = (t >= o) ? s[t - o] : 0;
        __syncthreads();
        s[t] += tmp;
        __syncthreads();
    }
    int run = s[t] - sum;   // exclusive base for this thread's 4 buckets
    #pragma unroll
    for (int j = 0; j < 4; j++) {
        int b = t * 4 + j;
        if (b < NBKT) { bstart[b] = run; gCursor[b] = run; }
        run += c[j];
    }
}

// ---------- phase 1c: multisplit scatter to coarse bucket regions ----------
__global__ void k_bscatter(const int* __restrict__ src, const int* __restrict__ dst,
                           const float* __restrict__ ew, int* __restrict__ gCursor,
                           int2* __restrict__ bbuf) {
    __shared__ int cnt[NBKT];
    __shared__ int base[NBKT];
    for (int i = threadIdx.x; i < NBKT; i += 256) cnt[i] = 0;
    __syncthreads();
    int e0 = blockIdx.x * TILE;
    int myb[8]; int2 rec[8];
    #pragma unroll
    for (int j = 0; j < 8; j++) {
        int e = e0 + j * 256 + threadIdx.x;
        myb[j] = -1;
        if (e < NE) {
            int d = dst[e];
            int b = d >> 6;
            myb[j] = b;
            rec[j] = make_int2(src[e] | ((d & 63) << 16), __float_as_int(ew[e]));
            atomicAdd(&cnt[b], 1);
        }
    }
    __syncthreads();
    for (int i = threadIdx.x; i < NBKT; i += 256)
        base[i] = cnt[i] ? atomicAdd(&gCursor[i], cnt[i]) : 0;
    __syncthreads();
    #pragma unroll
    for (int j = 0; j < 8; j++) {
        if (myb[j] >= 0) {
            int pos = atomicAdd(&base[myb[j]], 1);
            bbuf[pos] = rec[j];
        }
    }
}

// ---------- phase 2: per-bucket sort into final CSR; emits off/deg ----------
__global__ void k_bsort(const int* __restrict__ bcnt, const int* __restrict__ bstart,
                        const int2* __restrict__ bbuf,
                        int* __restrict__ off, int* __restrict__ deg,
                        int2* __restrict__ pairP) {
    int b = blockIdx.x;
    int st = bstart[b], ce = bcnt[b];
    __shared__ int h[64];
    __shared__ int cur[64];
    if (threadIdx.x < 64) h[threadIdx.x] = 0;
    __syncthreads();
    for (int i = threadIdx.x; i < ce; i += 256)
        atomicAdd(&h[(bbuf[st + i].x >> 16) & 63], 1);
    __syncthreads();
    if (threadIdx.x < 64) {
        int v = h[threadIdx.x];
        int inc = v;
        #pragma unroll
        for (int o = 1; o < 64; o <<= 1) {
            int tmp = __shfl_up(inc, o);
            if (threadIdx.x >= o) inc += tmp;
        }
        int exc = st + inc - v;
        cur[threadIdx.x] = exc;
        int n = b * 64 + threadIdx.x;
        if (n < NN) { off[n] = exc; deg[n] = v; }
    }
    __syncthreads();
    for (int i = threadIdx.x; i < ce; i += 256) {
        int2 r = bbuf[st + i];
        int pos = atomicAdd(&cur[(r.x >> 16) & 63], 1);
        pairP[pos] = make_int2(r.x & 0xFFFF, r.y);
    }
}

// ---------- fused node linear: wave = matrix (0=q,1=k,2=v,3=s), W column in regs ----------
__global__ void k_linear(const float* __restrict__ xin, int relu_in,
                         const float* __restrict__ Wq, const float* __restrict__ bq,
                         const float* __restrict__ Wk, const float* __restrict__ bk,
                         const float* __restrict__ Wv, const float* __restrict__ bv,
                         const float* __restrict__ Ws, const float* __restrict__ bs,
                         float* __restrict__ q, __half* __restrict__ kvh,
                         float* __restrict__ agg) {
    int tid = threadIdx.x;
    int mat = tid >> 6, feat = tid & 63;
    const float* W = mat == 0 ? Wq : mat == 1 ? Wk : mat == 2 ? Wv : Ws;
    const float* b = mat == 0 ? bq : mat == 1 ? bk : mat == 2 ? bv : bs;

    float wcol[64];
    #pragma unroll
    for (int kk = 0; kk < 64; kk++) wcol[kk] = W[kk * 64 + feat];
    float bias = b[feat];

    __shared__ float sx[16 * 64];
    const float4* x4 = (const float4*)xin;

    for (int n0 = blockIdx.x * 16; n0 < NN; n0 += gridDim.x * 16) {
        __syncthreads();
        float4 xv = x4[n0 * 16 + tid];   // 256 threads x float4 = 16 nodes
        if (relu_in) {
            xv.x = fmaxf(xv.x, 0.f); xv.y = fmaxf(xv.y, 0.f);
            xv.z = fmaxf(xv.z, 0.f); xv.w = fmaxf(xv.w, 0.f);
        }
        ((float4*)sx)[tid] = xv;
        __syncthreads();
        for (int c = 0; c < 16; c++) {
            const float4* sxc = (const float4*)(sx + c * 64);
            float acc = bias;
            #pragma unroll
            for (int k4 = 0; k4 < 16; k4++) {
                float4 v = sxc[k4];
                acc = fmaf(v.x, wcol[4 * k4 + 0], acc);
                acc = fmaf(v.y, wcol[4 * k4 + 1], acc);
                acc = fmaf(v.z, wcol[4 * k4 + 2], acc);
                acc = fmaf(v.w, wcol[4 * k4 + 3], acc);
            }
            int nn = n0 + c;
            if (mat == 0)      q[nn * 64 + feat] = acc;
            else if (mat == 1) kvh[nn * 128 + feat] = __float2half(acc);
            else if (mat == 2) kvh[nn * 128 + 64 + feat] = __float2half(acc);
            else               agg[nn * 64 + feat] = acc;
        }
    }
}

// ---------- fused edge kernel: wave per dst node, 4 edges in flight, fp16 kv ----------
__global__ void k_edge(const int2* __restrict__ pairP,
                       const int* __restrict__ off, const int* __restrict__ deg,
                       const float* __restrict__ q, const __half* __restrict__ kvh,
                       const float* __restrict__ We, float* __restrict__ agg) {
    long gid = (long)blockIdx.x * 256 + threadIdx.x;
    int n = (int)(gid >> 6);
    if (n >= NN) return;
    int lane = threadIdx.x & 63;
    int g = lane >> 4, l = lane & 15;

    const float4* q4  = (const float4*)q;
    const float4* We4 = (const float4*)We;
    const uint2*  kv8 = (const uint2*)kvh;   // node row = 32 uint2 (16 k + 16 v)
    float4 qv  = q4[n * 16 + l];
    float4 wev = We4[l];
    int st = off[n], dg = deg[n];
    int nit = (dg + 3) >> 2;

    float m = -INFINITY, den = 0.f;
    float4 acc = make_float4(0.f, 0.f, 0.f, 0.f);

    // 2-deep software pipeline per 16-lane group
    bool vaA = (g < dg), vaB = (4 + g < dg);
    int2 prA = make_int2(0, 0), prB = make_int2(0, 0);
    uint2 kuA = make_uint2(0, 0), vuA = kuA, kuB = kuA, vuB = kuA;
    if (vaA) prA = pairP[st + g];
    if (vaB) prB = pairP[st + 4 + g];
    if (vaA) { kuA = kv8[prA.x * 32 + l]; vuA = kv8[prA.x * 32 + 16 + l]; }

    for (int i = 0; i < nit; i++) {
        bool vaC = (4 * (i + 2) + g < dg);
        int2 prC = make_int2(0, 0);
        if (vaC) prC = pairP[st + 4 * (i + 2) + g];
        if (vaB) { kuB = kv8[prB.x * 32 + l]; vuB = kv8[prB.x * 32 + 16 + l]; }
        if (vaA) {
            float w = __int_as_float(prA.y);
            float2 k0 = __half22float2(*(const __half2*)&kuA.x);
            float2 k1 = __half22float2(*(const __half2*)&kuA.y);
            float2 v0 = __half22float2(*(const __half2*)&vuA.x);
            float2 v1 = __half22float2(*(const __half2*)&vuA.y);
            float t =            qv.x * fmaf(w, wev.x, k0.x);
            t = fmaf(qv.y, fmaf(w, wev.y, k0.y), t);
            t = fmaf(qv.z, fmaf(w, wev.z, k1.x), t);
            t = fmaf(qv.w, fmaf(w, wev.w, k1.y), t);
            t += __shfl_xor(t, 1); t += __shfl_xor(t, 2);
            t += __shfl_xor(t, 4); t += __shfl_xor(t, 8);
            t *= 0.125f;
            float nm = fmaxf(m, t);
            float sc = __expf(m - nm);   // m=-inf,t finite -> 0, no NaN
            float p  = __expf(t - nm);
            den = den * sc + p;
            acc.x = fmaf(p, fmaf(w, wev.x, v0.x), acc.x * sc);
            acc.y = fmaf(p, fmaf(w, wev.y, v0.y), acc.y * sc);
            acc.z = fmaf(p, fmaf(w, wev.z, v1.x), acc.z * sc);
            acc.w = fmaf(p, fmaf(w, wev.w, v1.y), acc.w * sc);
            m = nm;
        }
        vaA = vaB; prA = prB; kuA = kuB; vuA = vuB;
        vaB = vaC; prB = prC;
    }

    // merge the 4 group softmax states (xor 16, then 32)
    #pragma unroll
    for (int o = 16; o <= 32; o <<= 1) {
        float  om   = __shfl_xor(m, o);
        float  oden = __shfl_xor(den, o);
        float4 oacc;
        oacc.x = __shfl_xor(acc.x, o); oacc.y = __shfl_xor(acc.y, o);
        oacc.z = __shfl_xor(acc.z, o); oacc.w = __shfl_xor(acc.w, o);
        float nm = fmaxf(m, om);
        float s1 = __expf(fmaxf(m - nm, -80.f));   // NaN-guard for -inf - -inf
        float s2 = __expf(fmaxf(om - nm, -80.f));
        den = den * s1 + oden * s2;
        acc.x = acc.x * s1 + oacc.x * s2;
        acc.y = acc.y * s1 + oacc.y * s2;
        acc.z = acc.z * s1 + oacc.z * s2;
        acc.w = acc.w * s1 + oacc.w * s2;
        m = nm;
    }

    if (g == 0) {
        float inv = 1.f / fmaxf(den, 1e-16f);
        float4* agg4 = (float4*)agg;
        float4 a = agg4[n * 16 + l];
        a.x = fmaf(acc.x, inv, a.x);
        a.y = fmaf(acc.y, inv, a.y);
        a.z = fmaf(acc.z, inv, a.z);
        a.w = fmaf(acc.w, inv, a.w);
        agg4[n * 16 + l] = a;
    }
}

// ---------- pool + head: block per graph, batch is sorted ----------
__global__ void k_final(const float* __restrict__ h, const int* __restrict__ batch,
                        const float* __restrict__ Wl, const float* __restrict__ bl,
                        float* __restrict__ out) {
    int g = blockIdx.x;
    int tid = threadIdx.x;
    int lo = 0, hi = NN;
    while (lo < hi) { int mid = (lo + hi) >> 1; if (batch[mid] < g) lo = mid + 1; else hi = mid; }
    int s0 = lo;
    hi = NN;
    while (lo < hi) { int mid = (lo + hi) >> 1; if (batch[mid] < g + 1) lo = mid + 1; else hi = mid; }
    int s1 = lo;

    int sub = tid >> 6, lane = tid & 63;
    float a = 0.f;
    for (int n = s0 + sub; n < s1; n += 4) a += fmaxf(h[n * 64 + lane], 0.f);
    __shared__ float sred[4][64];
    sred[sub][lane] = a;
    __syncthreads();
    if (tid < 64) {
        float p = (sred[0][tid] + sred[1][tid] + sred[2][tid] + sred[3][tid])
                  / fmaxf((float)(s1 - s0), 1.f);
        float a0 = p * Wl[tid * 2 + 0];
        float a1 = p * Wl[tid * 2 + 1];
        #pragma unroll
        for (int o = 1; o < 64; o <<= 1) { a0 += __shfl_xor(a0, o); a1 += __shfl_xor(a1, o); }
        if (tid == 0) { out[g * 2 + 0] = a0 + bl[0]; out[g * 2 + 1] = a1 + bl[1]; }
    }
}

extern "C" void kernel_launch(void* const* d_in, const int* in_sizes, int n_in,
                              void* d_out, int out_size, void* d_ws, size_t ws_size,
                              hipStream_t stream) {
    const float* x    = (const float*)d_in[0];
    const int*   ei   = (const int*)d_in[1];
    const float* ew   = (const float*)d_in[2];
    const int*   batch= (const int*)d_in[3];
    const float *Wq1 = (const float*)d_in[4],  *bq1 = (const float*)d_in[5],
                *Wk1 = (const float*)d_in[6],  *bk1 = (const float*)d_in[7],
                *Wv1 = (const float*)d_in[8],  *bv1 = (const float*)d_in[9],
                *We1 = (const float*)d_in[10], *Ws1 = (const float*)d_in[11],
                *bs1 = (const float*)d_in[12],
                *Wq2 = (const float*)d_in[13], *bq2 = (const float*)d_in[14],
                *Wk2 = (const float*)d_in[15], *bk2 = (const float*)d_in[16],
                *Wv2 = (const float*)d_in[17], *bv2 = (const float*)d_in[18],
                *We2 = (const float*)d_in[19], *Ws2 = (const float*)d_in[20],
                *bs2 = (const float*)d_in[21],
                *Wl  = (const float*)d_in[22], *bl  = (const float*)d_in[23];
    const int* src = ei;        // edge_index[0]
    const int* dst = ei + NE;   // edge_index[1]
    float* out = (float*)d_out;

    float* p = (float*)d_ws;
    float* q    = p; p += (size_t)NN * 64;
    float* agg1 = p; p += (size_t)NN * 64;
    float* agg2 = p; p += (size_t)NN * 64;
    __half* kvh = (__half*)p; p += (size_t)NN * 64;   // NN*128 halfs
    int2* bbuf  = (int2*)p;  p += (size_t)NE * 2;
    int2* pairP = (int2*)p;  p += (size_t)NE * 2;
    int* ip = (int*)p;
    int* bcnt    = ip; ip += NBKT;
    int* bstart  = ip; ip += NBKT;
    int* gCursor = ip; ip += NBKT;
    int* off     = ip; ip += NN;
    int* deg     = ip; ip += NN;

    dim3 b256(256);
    int wgrid = (int)(((long)NN * 64 + 255) / 256);     // wave per node: 12500

    // ---- CSR build via two-level multisplit (shared by both layers) ----
    k_zero<<<4, b256, 0, stream>>>(bcnt);
    k_bcount<<<NTB, b256, 0, stream>>>(dst, bcnt);
    k_bscan<<<1, b256, 0, stream>>>(bcnt, bstart, gCursor);
    k_bscatter<<<NTB, b256, 0, stream>>>(src, dst, ew, gCursor, bbuf);
    k_bsort<<<NBKT, b256, 0, stream>>>(bcnt, bstart, bbuf, off, deg, pairP);

    // ---- layer 1 ----
    k_linear<<<512, b256, 0, stream>>>(x, 0, Wq1, bq1, Wk1, bk1, Wv1, bv1, Ws1, bs1,
                                       q, kvh, agg1);
    k_edge<<<wgrid, b256, 0, stream>>>(pairP, off, deg, q, kvh, We1, agg1);

    // ---- layer 2 (input = relu(agg1), applied on read) ----
    k_linear<<<512, b256, 0, stream>>>(agg1, 1, Wq2, bq2, Wk2, bk2, Wv2, bv2, Ws2, bs2,
                                       q, kvh, agg2);
    k_edge<<<wgrid, b256, 0, stream>>>(pairP, off, deg, q, kvh, We2, agg2);

    // ---- pool + head (relu applied on read of agg2) ----
    k_final<<<NG, b256, 0, stream>>>(agg2, batch, Wl, bl, out);
}

// Round 5
// 297.466 us; speedup vs baseline: 4.3670x; 1.1055x over previous
//
#include <hip/hip_runtime.h>
#include <hip/hip_fp16.h>

#define NN 50000
#define NE 1250000
#define NG 256
#define NBKT 782          // ceil(NN/64) buckets of 64 nodes
#define TILE 2048         // edges per multisplit block
#define NTB 611           // ceil(NE/TILE)

#define QSCALE 0.18033688011112042f   // log2(e)/8
#define EXP2 __builtin_amdgcn_exp2f

// ---------- zero bucket counters ----------
__global__ void k_zero(int* bcnt) {
    int i = blockIdx.x * 256 + threadIdx.x;
    if (i < NBKT) bcnt[i] = 0;
}

// ---------- phase 1a: bucket histogram ----------
__global__ void k_bcount(const int* __restrict__ dst, int* __restrict__ bcnt) {
    __shared__ int cnt[NBKT];
    for (int i = threadIdx.x; i < NBKT; i += 256) cnt[i] = 0;
    __syncthreads();
    int e0 = blockIdx.x * TILE;
    #pragma unroll
    for (int j = 0; j < 8; j++) {
        int e = e0 + j * 256 + threadIdx.x;
        if (e < NE) atomicAdd(&cnt[dst[e] >> 6], 1);
    }
    __syncthreads();
    for (int i = threadIdx.x; i < NBKT; i += 256)
        if (cnt[i]) atomicAdd(&bcnt[i], cnt[i]);
}

// ---------- phase 1b: scan bucket counts -> bases; off sentinel ----------
__global__ void k_bscan(const int* __restrict__ bcnt, int* __restrict__ bstart,
                        int* __restrict__ gCursor, int* __restrict__ off) {
    __shared__ int s[256];
    int t = threadIdx.x;
    int c[4]; int sum = 0;
    #pragma unroll
    for (int j = 0; j < 4; j++) {
        int b = t * 4 + j;
        c[j] = (b < NBKT) ? bcnt[b] : 0;
        sum += c[j];
    }
    s[t] = sum;
    __syncthreads();
    for (int o = 1; o < 256; o <<= 1) {
        int tmp = (t >= o) ? s[t - o] : 0;
        __syncthreads();
        s[t] += tmp;
        __syncthreads();
    }
    int run = s[t] - sum;   // exclusive base for this thread's 4 buckets
    #pragma unroll
    for (int j = 0; j < 4; j++) {
        int b = t * 4 + j;
        if (b < NBKT) { bstart[b] = run; gCursor[b] = run; }
        run += c[j];
    }
    if (t == 0) off[NN] = NE;   // CSR sentinel
}

// ---------- phase 1c: multisplit scatter to coarse bucket regions ----------
__global__ void k_bscatter(const int* __restrict__ src, const int* __restrict__ dst,
                           const float* __restrict__ ew, int* __restrict__ gCursor,
                           int2* __restrict__ bbuf) {
    __shared__ int cnt[NBKT];
    __shared__ int base[NBKT];
    for (int i = threadIdx.x; i < NBKT; i += 256) cnt[i] = 0;
    __syncthreads();
    int e0 = blockIdx.x * TILE;
    int myb[8]; int2 rec[8];
    #pragma unroll
    for (int j = 0; j < 8; j++) {
        int e = e0 + j * 256 + threadIdx.x;
        myb[j] = -1;
        if (e < NE) {
            int d = dst[e];
            int b = d >> 6;
            myb[j] = b;
            rec[j] = make_int2(src[e] | ((d & 63) << 16), __float_as_int(ew[e]));
            atomicAdd(&cnt[b], 1);
        }
    }
    __syncthreads();
    for (int i = threadIdx.x; i < NBKT; i += 256)
        base[i] = cnt[i] ? atomicAdd(&gCursor[i], cnt[i]) : 0;
    __syncthreads();
    #pragma unroll
    for (int j = 0; j < 8; j++) {
        if (myb[j] >= 0) {
            int pos = atomicAdd(&base[myb[j]], 1);
            bbuf[pos] = rec[j];
        }
    }
}

// ---------- phase 2: per-bucket sort into final CSR (packed 4B pairs); emits off ----------
__global__ void k_bsort(const int* __restrict__ bcnt, const int* __restrict__ bstart,
                        const int2* __restrict__ bbuf,
                        int* __restrict__ off, unsigned* __restrict__ pairP) {
    int b = blockIdx.x;
    int st = bstart[b], ce = bcnt[b];
    __shared__ int h[64];
    __shared__ int cur[64];
    if (threadIdx.x < 64) h[threadIdx.x] = 0;
    __syncthreads();
    for (int i = threadIdx.x; i < ce; i += 256)
        atomicAdd(&h[(bbuf[st + i].x >> 16) & 63], 1);
    __syncthreads();
    if (threadIdx.x < 64) {
        int v = h[threadIdx.x];
        int inc = v;
        #pragma unroll
        for (int o = 1; o < 64; o <<= 1) {
            int tmp = __shfl_up(inc, o);
            if (threadIdx.x >= o) inc += tmp;
        }
        int exc = st + inc - v;
        cur[threadIdx.x] = exc;
        int n = b * 64 + threadIdx.x;
        if (n < NN) off[n] = exc;
    }
    __syncthreads();
    for (int i = threadIdx.x; i < ce; i += 256) {
        int2 r = bbuf[st + i];
        int pos = atomicAdd(&cur[(r.x >> 16) & 63], 1);
        unsigned hw = (unsigned)__half_as_ushort(__float2half(__int_as_float(r.y)));
        pairP[pos] = (unsigned)(r.x & 0xFFFF) | (hw << 16);
    }
}

// ---------- fused node linear: wave = matrix (0=q,1=k,2=v,3=s), W column in regs ----------
// q written pre-scaled by log2(e)/8; k,v written fp16 interleaved (16B chunk = 4k+4v halfs)
__global__ void k_linear(const float* __restrict__ xin, int relu_in,
                         const float* __restrict__ Wq, const float* __restrict__ bq,
                         const float* __restrict__ Wk, const float* __restrict__ bk,
                         const float* __restrict__ Wv, const float* __restrict__ bv,
                         const float* __restrict__ Ws, const float* __restrict__ bs,
                         float* __restrict__ q, __half* __restrict__ kvh,
                         float* __restrict__ agg) {
    int tid = threadIdx.x;
    int mat = tid >> 6, feat = tid & 63;
    const float* W = mat == 0 ? Wq : mat == 1 ? Wk : mat == 2 ? Wv : Ws;
    const float* b = mat == 0 ? bq : mat == 1 ? bk : mat == 2 ? bv : bs;

    float wcol[64];
    #pragma unroll
    for (int kk = 0; kk < 64; kk++) wcol[kk] = W[kk * 64 + feat];
    float bias = b[feat];
    int kvoff = (feat >> 2) * 8 + (feat & 3) + (mat == 2 ? 4 : 0);

    __shared__ float sx[16 * 64];
    const float4* x4 = (const float4*)xin;

    for (int n0 = blockIdx.x * 16; n0 < NN; n0 += gridDim.x * 16) {
        __syncthreads();
        float4 xv = x4[n0 * 16 + tid];   // 256 threads x float4 = 16 nodes
        if (relu_in) {
            xv.x = fmaxf(xv.x, 0.f); xv.y = fmaxf(xv.y, 0.f);
            xv.z = fmaxf(xv.z, 0.f); xv.w = fmaxf(xv.w, 0.f);
        }
        ((float4*)sx)[tid] = xv;
        __syncthreads();
        for (int c = 0; c < 16; c++) {
            const float4* sxc = (const float4*)(sx + c * 64);
            float acc = bias;
            #pragma unroll
            for (int k4 = 0; k4 < 16; k4++) {
                float4 v = sxc[k4];
                acc = fmaf(v.x, wcol[4 * k4 + 0], acc);
                acc = fmaf(v.y, wcol[4 * k4 + 1], acc);
                acc = fmaf(v.z, wcol[4 * k4 + 2], acc);
                acc = fmaf(v.w, wcol[4 * k4 + 3], acc);
            }
            int nn = n0 + c;
            if (mat == 0)      q[nn * 64 + feat] = acc * QSCALE;
            else if (mat == 3) agg[nn * 64 + feat] = acc;
            else               kvh[nn * 128 + kvoff] = __float2half(acc);
        }
    }
}

// ---------- fused edge kernel: wave per dst node, 4 edges in flight ----------
__global__ void k_edge(const unsigned* __restrict__ pairP,
                       const int* __restrict__ off,
                       const float* __restrict__ q, const uint4* __restrict__ kv16,
                       const float* __restrict__ We, float* __restrict__ agg) {
    long gid = (long)blockIdx.x * 256 + threadIdx.x;
    int n = (int)(gid >> 6);
    if (n >= NN) return;
    int lane = threadIdx.x & 63;
    int g = lane >> 4, l = lane & 15;

    const float4* q4  = (const float4*)q;
    const float4* We4 = (const float4*)We;
    float4 qv  = q4[n * 16 + l];     // pre-scaled by log2e/8
    float4 wev = We4[l];
    int st = off[n], dg = off[n + 1] - st;

    // per-node scalar qWe (scaled domain)
    float qwe = qv.x * wev.x + qv.y * wev.y + qv.z * wev.z + qv.w * wev.w;
    qwe += __shfl_xor(qwe, 1); qwe += __shfl_xor(qwe, 2);
    qwe += __shfl_xor(qwe, 4); qwe += __shfl_xor(qwe, 8);

    float m = -INFINITY, den = 0.f, sw = 0.f;
    float4 acc = make_float4(0.f, 0.f, 0.f, 0.f);

    auto edge = [&](unsigned pr, uint4 kvr) {
        float w = __half2float(__ushort_as_half((unsigned short)(pr >> 16)));
        float2 k0 = __half22float2(*(const __half2*)&kvr.x);
        float2 k1 = __half22float2(*(const __half2*)&kvr.y);
        float2 v0 = __half22float2(*(const __half2*)&kvr.z);
        float2 v1 = __half22float2(*(const __half2*)&kvr.w);
        float t = qv.x * k0.x;
        t = fmaf(qv.y, k0.y, t);
        t = fmaf(qv.z, k1.x, t);
        t = fmaf(qv.w, k1.y, t);
        t += __shfl_xor(t, 1); t += __shfl_xor(t, 2);
        t += __shfl_xor(t, 4); t += __shfl_xor(t, 8);
        t = fmaf(w, qwe, t);
        float nm = fmaxf(m, t);
        float sc = EXP2(m - nm);     // m=-inf -> 0, no NaN (t finite)
        float p  = EXP2(t - nm);
        den = fmaf(den, sc, p);
        sw  = fmaf(sw,  sc, p * w);
        acc.x = fmaf(acc.x, sc, p * v0.x);
        acc.y = fmaf(acc.y, sc, p * v0.y);
        acc.z = fmaf(acc.z, sc, p * v1.x);
        acc.w = fmaf(acc.w, sc, p * v1.y);
        m = nm;
    };

    int nfull = dg >> 2;
    if (nfull) {
        unsigned pr = pairP[st + g];
        uint4 kvr = kv16[(pr & 0xFFFF) * 16 + l];
        for (int i = 1; i < nfull; i++) {
            unsigned prN = pairP[st + 4 * i + g];
            uint4 kvN = kv16[(prN & 0xFFFF) * 16 + l];
            edge(pr, kvr);
            pr = prN; kvr = kvN;
        }
        edge(pr, kvr);
    }
    int tl = 4 * nfull + g;
    if (tl < dg) {
        unsigned pr = pairP[st + tl];
        uint4 kvr = kv16[(pr & 0xFFFF) * 16 + l];
        edge(pr, kvr);
    }

    // merge the 4 group softmax states (xor 16, then 32)
    #pragma unroll
    for (int o = 16; o <= 32; o <<= 1) {
        float  om   = __shfl_xor(m, o);
        float  oden = __shfl_xor(den, o);
        float  osw  = __shfl_xor(sw, o);
        float4 oacc;
        oacc.x = __shfl_xor(acc.x, o); oacc.y = __shfl_xor(acc.y, o);
        oacc.z = __shfl_xor(acc.z, o); oacc.w = __shfl_xor(acc.w, o);
        float nm = fmaxf(m, om);
        float s1 = EXP2(fmaxf(m - nm, -126.f));   // NaN-guard for -inf - -inf
        float s2 = EXP2(fmaxf(om - nm, -126.f));
        den = den * s1 + oden * s2;
        sw  = sw  * s1 + osw  * s2;
        acc.x = acc.x * s1 + oacc.x * s2;
        acc.y = acc.y * s1 + oacc.y * s2;
        acc.z = acc.z * s1 + oacc.z * s2;
        acc.w = acc.w * s1 + oacc.w * s2;
        m = nm;
    }

    if (g == 0) {
        float inv = 1.f / fmaxf(den, 1e-16f);
        float swi = sw * inv;
        float4* agg4 = (float4*)agg;
        float4 a = agg4[n * 16 + l];
        a.x = fmaf(acc.x, inv, fmaf(swi, wev.x, a.x));
        a.y = fmaf(acc.y, inv, fmaf(swi, wev.y, a.y));
        a.z = fmaf(acc.z, inv, fmaf(swi, wev.z, a.z));
        a.w = fmaf(acc.w, inv, fmaf(swi, wev.w, a.w));
        agg4[n * 16 + l] = a;
    }
}

// ---------- pool + head: block per graph, batch is sorted ----------
__global__ void k_final(const float* __restrict__ h, const int* __restrict__ batch,
                        const float* __restrict__ Wl, const float* __restrict__ bl,
                        float* __restrict__ out) {
    int g = blockIdx.x;
    int tid = threadIdx.x;
    int lo = 0, hi = NN;
    while (lo < hi) { int mid = (lo + hi) >> 1; if (batch[mid] < g) lo = mid + 1; else hi = mid; }
    int s0 = lo;
    hi = NN;
    while (lo < hi) { int mid = (lo + hi) >> 1; if (batch[mid] < g + 1) lo = mid + 1; else hi = mid; }
    int s1 = lo;

    int sub = tid >> 6, lane = tid & 63;
    float a = 0.f;
    for (int n = s0 + sub; n < s1; n += 4) a += fmaxf(h[n * 64 + lane], 0.f);
    __shared__ float sred[4][64];
    sred[sub][lane] = a;
    __syncthreads();
    if (tid < 64) {
        float p = (sred[0][tid] + sred[1][tid] + sred[2][tid] + sred[3][tid])
                  / fmaxf((float)(s1 - s0), 1.f);
        float a0 = p * Wl[tid * 2 + 0];
        float a1 = p * Wl[tid * 2 + 1];
        #pragma unroll
        for (int o = 1; o < 64; o <<= 1) { a0 += __shfl_xor(a0, o); a1 += __shfl_xor(a1, o); }
        if (tid == 0) { out[g * 2 + 0] = a0 + bl[0]; out[g * 2 + 1] = a1 + bl[1]; }
    }
}

extern "C" void kernel_launch(void* const* d_in, const int* in_sizes, int n_in,
                              void* d_out, int out_size, void* d_ws, size_t ws_size,
                              hipStream_t stream) {
    const float* x    = (const float*)d_in[0];
    const int*   ei   = (const int*)d_in[1];
    const float* ew   = (const float*)d_in[2];
    const int*   batch= (const int*)d_in[3];
    const float *Wq1 = (const float*)d_in[4],  *bq1 = (const float*)d_in[5],
                *Wk1 = (const float*)d_in[6],  *bk1 = (const float*)d_in[7],
                *Wv1 = (const float*)d_in[8],  *bv1 = (const float*)d_in[9],
                *We1 = (const float*)d_in[10], *Ws1 = (const float*)d_in[11],
                *bs1 = (const float*)d_in[12],
                *Wq2 = (const float*)d_in[13], *bq2 = (const float*)d_in[14],
                *Wk2 = (const float*)d_in[15], *bk2 = (const float*)d_in[16],
                *Wv2 = (const float*)d_in[17], *bv2 = (const float*)d_in[18],
                *We2 = (const float*)d_in[19], *Ws2 = (const float*)d_in[20],
                *bs2 = (const float*)d_in[21],
                *Wl  = (const float*)d_in[22], *bl  = (const float*)d_in[23];
    const int* src = ei;        // edge_index[0]
    const int* dst = ei + NE;   // edge_index[1]
    float* out = (float*)d_out;

    float* p = (float*)d_ws;
    float* q    = p; p += (size_t)NN * 64;
    float* agg1 = p; p += (size_t)NN * 64;
    float* agg2 = p; p += (size_t)NN * 64;
    __half* kvh = (__half*)p; p += (size_t)NN * 64;   // NN*128 halfs
    int2* bbuf  = (int2*)p;  p += (size_t)NE * 2;
    unsigned* pairP = (unsigned*)p; p += (size_t)NE;
    int* ip = (int*)p;
    int* bcnt    = ip; ip += NBKT;
    int* bstart  = ip; ip += NBKT;
    int* gCursor = ip; ip += NBKT;
    int* off     = ip; ip += NN + 1;

    dim3 b256(256);
    int wgrid = (int)(((long)NN * 64 + 255) / 256);     // wave per node: 12500

    // ---- CSR build via two-level multisplit (shared by both layers) ----
    k_zero<<<4, b256, 0, stream>>>(bcnt);
    k_bcount<<<NTB, b256, 0, stream>>>(dst, bcnt);
    k_bscan<<<1, b256, 0, stream>>>(bcnt, bstart, gCursor, off);
    k_bscatter<<<NTB, b256, 0, stream>>>(src, dst, ew, gCursor, bbuf);
    k_bsort<<<NBKT, b256, 0, stream>>>(bcnt, bstart, bbuf, off, pairP);

    // ---- layer 1 ----
    k_linear<<<512, b256, 0, stream>>>(x, 0, Wq1, bq1, Wk1, bk1, Wv1, bv1, Ws1, bs1,
                                       q, kvh, agg1);
    k_edge<<<wgrid, b256, 0, stream>>>(pairP, off, q, (const uint4*)kvh, We1, agg1);

    // ---- layer 2 (input = relu(agg1), applied on read) ----
    k_linear<<<512, b256, 0, stream>>>(agg1, 1, Wq2, bq2, Wk2, bk2, Wv2, bv2, Ws2, bs2,
                                       q, kvh, agg2);
    k_edge<<<wgrid, b256, 0, stream>>>(pairP, off, q, (const uint4*)kvh, We2, agg2);

    // ---- pool + head (relu applied on read of agg2) ----
    k_final<<<NG, b256, 0, stream>>>(agg2, batch, Wl, bl, out);
}

// Round 6
// 262.824 us; speedup vs baseline: 4.9426x; 1.1318x over previous
//
#include <hip/hip_runtime.h>
#include <hip/hip_fp16.h>

#define NN 50000
#define NE 1250000
#define NG 256
#define NBKT 782          // ceil(NN/64) buckets of 64 nodes
#define TILE 4096         // edges per multisplit block
#define NTB 306           // ceil(NE/TILE)

#define QSCALE 0.18033688011112042f   // log2(e)/8
#define EXP2 __builtin_amdgcn_exp2f

// ---------- zero bucket counters ----------
__global__ void k_zero(int* bcnt) {
    int i = blockIdx.x * 256 + threadIdx.x;
    if (i < NBKT) bcnt[i] = 0;
}

// ---------- phase 1a: bucket histogram ----------
__global__ void k_bcount(const int* __restrict__ dst, int* __restrict__ bcnt) {
    __shared__ int cnt[NBKT];
    for (int i = threadIdx.x; i < NBKT; i += 256) cnt[i] = 0;
    __syncthreads();
    int e0 = blockIdx.x * TILE;
    #pragma unroll
    for (int j = 0; j < 16; j++) {
        int e = e0 + j * 256 + threadIdx.x;
        if (e < NE) atomicAdd(&cnt[dst[e] >> 6], 1);
    }
    __syncthreads();
    for (int i = threadIdx.x; i < NBKT; i += 256)
        if (cnt[i]) atomicAdd(&bcnt[i], cnt[i]);
}

// ---------- phase 1b: scan bucket counts -> bases; off sentinel ----------
__global__ void k_bscan(const int* __restrict__ bcnt, int* __restrict__ bstart,
                        int* __restrict__ gCursor, int* __restrict__ off) {
    __shared__ int s[256];
    int t = threadIdx.x;
    int c[4]; int sum = 0;
    #pragma unroll
    for (int j = 0; j < 4; j++) {
        int b = t * 4 + j;
        c[j] = (b < NBKT) ? bcnt[b] : 0;
        sum += c[j];
    }
    s[t] = sum;
    __syncthreads();
    for (int o = 1; o < 256; o <<= 1) {
        int tmp = (t >= o) ? s[t - o] : 0;
        __syncthreads();
        s[t] += tmp;
        __syncthreads();
    }
    int run = s[t] - sum;   // exclusive base for this thread's 4 buckets
    #pragma unroll
    for (int j = 0; j < 4; j++) {
        int b = t * 4 + j;
        if (b < NBKT) { bstart[b] = run; gCursor[b] = run; }
        run += c[j];
    }
    if (t == 0) off[NN] = NE;   // CSR sentinel
}

// ---------- phase 1c: multisplit scatter to coarse bucket regions ----------
// rec.x = src (16b) | (d&63)<<16 | bucket<<22
__global__ void k_bscatter(const int* __restrict__ src, const int* __restrict__ dst,
                           const float* __restrict__ ew, int* __restrict__ gCursor,
                           int2* __restrict__ bbuf) {
    __shared__ int cnt[NBKT];
    __shared__ int base[NBKT];
    for (int i = threadIdx.x; i < NBKT; i += 256) cnt[i] = 0;
    __syncthreads();
    int e0 = blockIdx.x * TILE;
    int2 rec[16];
    #pragma unroll
    for (int j = 0; j < 16; j++) {
        int e = e0 + j * 256 + threadIdx.x;
        if (e < NE) {
            int d = dst[e];
            int b = d >> 6;
            rec[j] = make_int2(src[e] | ((d & 63) << 16) | (b << 22), __float_as_int(ew[e]));
            atomicAdd(&cnt[b], 1);
        } else rec[j].x = -1;
    }
    __syncthreads();
    for (int i = threadIdx.x; i < NBKT; i += 256)
        base[i] = cnt[i] ? atomicAdd(&gCursor[i], cnt[i]) : 0;
    __syncthreads();
    #pragma unroll
    for (int j = 0; j < 16; j++) {
        if (rec[j].x != -1) {
            int b = ((unsigned)rec[j].x) >> 22;
            int pos = atomicAdd(&base[b], 1);
            bbuf[pos] = rec[j];
        }
    }
}

// ---------- phase 2: per-bucket sort into final CSR (packed 4B pairs); emits off ----------
__global__ void k_bsort(const int* __restrict__ bcnt, const int* __restrict__ bstart,
                        const int2* __restrict__ bbuf,
                        int* __restrict__ off, unsigned* __restrict__ pairP) {
    int b = blockIdx.x;
    int st = bstart[b], ce = bcnt[b];
    __shared__ int h[64];
    __shared__ int cur[64];
    if (threadIdx.x < 64) h[threadIdx.x] = 0;
    __syncthreads();
    for (int i = threadIdx.x; i < ce; i += 256)
        atomicAdd(&h[(bbuf[st + i].x >> 16) & 63], 1);
    __syncthreads();
    if (threadIdx.x < 64) {
        int v = h[threadIdx.x];
        int inc = v;
        #pragma unroll
        for (int o = 1; o < 64; o <<= 1) {
            int tmp = __shfl_up(inc, o);
            if (threadIdx.x >= o) inc += tmp;
        }
        int exc = st + inc - v;
        cur[threadIdx.x] = exc;
        int n = b * 64 + threadIdx.x;
        if (n < NN) off[n] = exc;
    }
    __syncthreads();
    for (int i = threadIdx.x; i < ce; i += 256) {
        int2 r = bbuf[st + i];
        int pos = atomicAdd(&cur[(r.x >> 16) & 63], 1);
        unsigned hw = (unsigned)__half_as_ushort(__float2half(__int_as_float(r.y)));
        pairP[pos] = (unsigned)(r.x & 0xFFFF) | (hw << 16);
    }
}

// ---------- fused node linear: wave = matrix (0=q,1=k,2=v,3=s), W column in regs ----------
// q written pre-scaled by log2(e)/8; kv row = [64 k-halfs][64 v-halfs]
__global__ void k_linear(const float* __restrict__ xin, int relu_in,
                         const float* __restrict__ Wq, const float* __restrict__ bq,
                         const float* __restrict__ Wk, const float* __restrict__ bk,
                         const float* __restrict__ Wv, const float* __restrict__ bv,
                         const float* __restrict__ Ws, const float* __restrict__ bs,
                         float* __restrict__ q, __half* __restrict__ kvh,
                         float* __restrict__ agg) {
    int tid = threadIdx.x;
    int mat = tid >> 6, feat = tid & 63;
    const float* W = mat == 0 ? Wq : mat == 1 ? Wk : mat == 2 ? Wv : Ws;
    const float* b = mat == 0 ? bq : mat == 1 ? bk : mat == 2 ? bv : bs;

    float wcol[64];
    #pragma unroll
    for (int kk = 0; kk < 64; kk++) wcol[kk] = W[kk * 64 + feat];
    float bias = b[feat];
    int kvoff = feat + (mat == 2 ? 64 : 0);

    __shared__ float sx[16 * 64];
    const float4* x4 = (const float4*)xin;

    for (int n0 = blockIdx.x * 16; n0 < NN; n0 += gridDim.x * 16) {
        __syncthreads();
        float4 xv = x4[n0 * 16 + tid];   // 256 threads x float4 = 16 nodes
        if (relu_in) {
            xv.x = fmaxf(xv.x, 0.f); xv.y = fmaxf(xv.y, 0.f);
            xv.z = fmaxf(xv.z, 0.f); xv.w = fmaxf(xv.w, 0.f);
        }
        ((float4*)sx)[tid] = xv;
        __syncthreads();
        for (int c = 0; c < 16; c++) {
            const float4* sxc = (const float4*)(sx + c * 64);
            float acc = bias;
            #pragma unroll
            for (int k4 = 0; k4 < 16; k4++) {
                float4 v = sxc[k4];
                acc = fmaf(v.x, wcol[4 * k4 + 0], acc);
                acc = fmaf(v.y, wcol[4 * k4 + 1], acc);
                acc = fmaf(v.z, wcol[4 * k4 + 2], acc);
                acc = fmaf(v.w, wcol[4 * k4 + 3], acc);
            }
            int nn = n0 + c;
            if (mat == 0)      q[nn * 64 + feat] = acc * QSCALE;
            else if (mat == 3) agg[nn * 64 + feat] = acc;
            else               kvh[nn * 128 + kvoff] = __float2half(acc);
        }
    }
}

// ---------- fused edge kernel: wave per dst node, 8-lane groups, no-max softmax ----------
__global__ void k_edge(const unsigned* __restrict__ pairP,
                       const int* __restrict__ off,
                       const float* __restrict__ q, const uint4* __restrict__ kv16,
                       const float* __restrict__ We, float* __restrict__ agg) {
    long gid = (long)blockIdx.x * 256 + threadIdx.x;
    int n = (int)(gid >> 6);
    if (n >= NN) return;
    int lane = threadIdx.x & 63;
    int g = lane >> 3, l = lane & 7;   // 8 groups x 8 lanes

    // per-lane 8 q feats (f32, pre-scaled), 8 We feats
    const float4* qp = (const float4*)(q + n * 64 + l * 8);
    float4 qa = qp[0], qb = qp[1];
    const float4* wp = (const float4*)(We + l * 8);
    float4 wa = wp[0], wb = wp[1];

    int st = off[n], dg = off[n + 1] - st;

    // per-node scalar qWe (scaled domain)
    float qwe = qa.x * wa.x + qa.y * wa.y + qa.z * wa.z + qa.w * wa.w
              + qb.x * wb.x + qb.y * wb.y + qb.z * wb.z + qb.w * wb.w;
    qwe += __shfl_xor(qwe, 1); qwe += __shfl_xor(qwe, 2); qwe += __shfl_xor(qwe, 4);

    float den = 0.f, sw = 0.f;
    float acc[8] = {0.f, 0.f, 0.f, 0.f, 0.f, 0.f, 0.f, 0.f};

    auto edge = [&](unsigned pr, uint4 kk, uint4 vv) {
        float w = __half2float(__ushort_as_half((unsigned short)(pr >> 16)));
        float2 k0 = __half22float2(*(const __half2*)&kk.x);
        float2 k1 = __half22float2(*(const __half2*)&kk.y);
        float2 k2 = __half22float2(*(const __half2*)&kk.z);
        float2 k3 = __half22float2(*(const __half2*)&kk.w);
        float t = qa.x * k0.x;
        t = fmaf(qa.y, k0.y, t); t = fmaf(qa.z, k1.x, t); t = fmaf(qa.w, k1.y, t);
        t = fmaf(qb.x, k2.x, t); t = fmaf(qb.y, k2.y, t);
        t = fmaf(qb.z, k3.x, t); t = fmaf(qb.w, k3.y, t);
        t += __shfl_xor(t, 1); t += __shfl_xor(t, 2); t += __shfl_xor(t, 4);
        t = fmaf(w, qwe, t);
        float p = EXP2(t);             // no max-subtraction: shift-invariant, no overflow (|t| << 127)
        den += p;
        sw = fmaf(p, w, sw);
        float2 v0 = __half22float2(*(const __half2*)&vv.x);
        float2 v1 = __half22float2(*(const __half2*)&vv.y);
        float2 v2 = __half22float2(*(const __half2*)&vv.z);
        float2 v3 = __half22float2(*(const __half2*)&vv.w);
        acc[0] = fmaf(p, v0.x, acc[0]); acc[1] = fmaf(p, v0.y, acc[1]);
        acc[2] = fmaf(p, v1.x, acc[2]); acc[3] = fmaf(p, v1.y, acc[3]);
        acc[4] = fmaf(p, v2.x, acc[4]); acc[5] = fmaf(p, v2.y, acc[5]);
        acc[6] = fmaf(p, v3.x, acc[6]); acc[7] = fmaf(p, v3.y, acc[7]);
    };

    int nfull = dg >> 3;
    if (nfull) {
        unsigned pr = pairP[st + g];
        unsigned row = pr & 0xFFFFu;
        uint4 kk = kv16[row * 16 + l];
        uint4 vv = kv16[row * 16 + 8 + l];
        for (int i = 1; i < nfull; i++) {
            unsigned prN = pairP[st + i * 8 + g];
            unsigned rowN = prN & 0xFFFFu;
            uint4 kkN = kv16[rowN * 16 + l];
            uint4 vvN = kv16[rowN * 16 + 8 + l];
            edge(pr, kk, vv);
            pr = prN; kk = kkN; vv = vvN;
        }
        edge(pr, kk, vv);
    }
    int tl = nfull * 8 + g;
    if (tl < dg) {
        unsigned pr = pairP[st + tl];
        unsigned row = pr & 0xFFFFu;
        uint4 kk = kv16[row * 16 + l];
        uint4 vv = kv16[row * 16 + 8 + l];
        edge(pr, kk, vv);
    }

    // merge the 8 group states (pure adds)
    #pragma unroll
    for (int o = 8; o <= 32; o <<= 1) {
        den += __shfl_xor(den, o);
        sw  += __shfl_xor(sw, o);
        #pragma unroll
        for (int j = 0; j < 8; j++) acc[j] += __shfl_xor(acc[j], o);
    }

    if (g == 0) {
        float inv = 1.f / fmaxf(den, 1e-16f);
        float swi = sw * inv;
        float4* a4 = (float4*)(agg + n * 64 + l * 8);
        float4 a0 = a4[0], a1 = a4[1];
        a0.x = fmaf(acc[0], inv, fmaf(swi, wa.x, a0.x));
        a0.y = fmaf(acc[1], inv, fmaf(swi, wa.y, a0.y));
        a0.z = fmaf(acc[2], inv, fmaf(swi, wa.z, a0.z));
        a0.w = fmaf(acc[3], inv, fmaf(swi, wa.w, a0.w));
        a1.x = fmaf(acc[4], inv, fmaf(swi, wb.x, a1.x));
        a1.y = fmaf(acc[5], inv, fmaf(swi, wb.y, a1.y));
        a1.z = fmaf(acc[6], inv, fmaf(swi, wb.z, a1.z));
        a1.w = fmaf(acc[7], inv, fmaf(swi, wb.w, a1.w));
        a4[0] = a0; a4[1] = a1;
    }
}

// ---------- pool + head: block per graph, batch is sorted ----------
__global__ void k_final(const float* __restrict__ h, const int* __restrict__ batch,
                        const float* __restrict__ Wl, const float* __restrict__ bl,
                        float* __restrict__ out) {
    int g = blockIdx.x;
    int tid = threadIdx.x;
    int lo = 0, hi = NN;
    while (lo < hi) { int mid = (lo + hi) >> 1; if (batch[mid] < g) lo = mid + 1; else hi = mid; }
    int s0 = lo;
    hi = NN;
    while (lo < hi) { int mid = (lo + hi) >> 1; if (batch[mid] < g + 1) lo = mid + 1; else hi = mid; }
    int s1 = lo;

    int sub = tid >> 6, lane = tid & 63;
    float a = 0.f;
    for (int n = s0 + sub; n < s1; n += 4) a += fmaxf(h[n * 64 + lane], 0.f);
    __shared__ float sred[4][64];
    sred[sub][lane] = a;
    __syncthreads();
    if (tid < 64) {
        float p = (sred[0][tid] + sred[1][tid] + sred[2][tid] + sred[3][tid])
                  / fmaxf((float)(s1 - s0), 1.f);
        float a0 = p * Wl[tid * 2 + 0];
        float a1 = p * Wl[tid * 2 + 1];
        #pragma unroll
        for (int o = 1; o < 64; o <<= 1) { a0 += __shfl_xor(a0, o); a1 += __shfl_xor(a1, o); }
        if (tid == 0) { out[g * 2 + 0] = a0 + bl[0]; out[g * 2 + 1] = a1 + bl[1]; }
    }
}

extern "C" void kernel_launch(void* const* d_in, const int* in_sizes, int n_in,
                              void* d_out, int out_size, void* d_ws, size_t ws_size,
                              hipStream_t stream) {
    const float* x    = (const float*)d_in[0];
    const int*   ei   = (const int*)d_in[1];
    const float* ew   = (const float*)d_in[2];
    const int*   batch= (const int*)d_in[3];
    const float *Wq1 = (const float*)d_in[4],  *bq1 = (const float*)d_in[5],
                *Wk1 = (const float*)d_in[6],  *bk1 = (const float*)d_in[7],
                *Wv1 = (const float*)d_in[8],  *bv1 = (const float*)d_in[9],
                *We1 = (const float*)d_in[10], *Ws1 = (const float*)d_in[11],
                *bs1 = (const float*)d_in[12],
                *Wq2 = (const float*)d_in[13], *bq2 = (const float*)d_in[14],
                *Wk2 = (const float*)d_in[15], *bk2 = (const float*)d_in[16],
                *Wv2 = (const float*)d_in[17], *bv2 = (const float*)d_in[18],
                *We2 = (const float*)d_in[19], *Ws2 = (const float*)d_in[20],
                *bs2 = (const float*)d_in[21],
                *Wl  = (const float*)d_in[22], *bl  = (const float*)d_in[23];
    const int* src = ei;        // edge_index[0]
    const int* dst = ei + NE;   // edge_index[1]
    float* out = (float*)d_out;

    float* p = (float*)d_ws;
    float* q    = p; p += (size_t)NN * 64;
    float* agg1 = p; p += (size_t)NN * 64;
    float* agg2 = p; p += (size_t)NN * 64;
    __half* kvh = (__half*)p; p += (size_t)NN * 64;   // NN*128 halfs
    int2* bbuf  = (int2*)p;  p += (size_t)NE * 2;
    unsigned* pairP = (unsigned*)p; p += (size_t)NE;
    int* ip = (int*)p;
    int* bcnt    = ip; ip += NBKT;
    int* bstart  = ip; ip += NBKT;
    int* gCursor = ip; ip += NBKT;
    int* off     = ip; ip += NN + 1;

    dim3 b256(256);
    int wgrid = (int)(((long)NN * 64 + 255) / 256);     // wave per node: 12500

    // ---- CSR build via two-level multisplit (shared by both layers) ----
    k_zero<<<4, b256, 0, stream>>>(bcnt);
    k_bcount<<<NTB, b256, 0, stream>>>(dst, bcnt);
    k_bscan<<<1, b256, 0, stream>>>(bcnt, bstart, gCursor, off);
    k_bscatter<<<NTB, b256, 0, stream>>>(src, dst, ew, gCursor, bbuf);
    k_bsort<<<NBKT, b256, 0, stream>>>(bcnt, bstart, bbuf, off, pairP);

    // ---- layer 1 ----
    k_linear<<<512, b256, 0, stream>>>(x, 0, Wq1, bq1, Wk1, bk1, Wv1, bv1, Ws1, bs1,
                                       q, kvh, agg1);
    k_edge<<<wgrid, b256, 0, stream>>>(pairP, off, q, (const uint4*)kvh, We1, agg1);

    // ---- layer 2 (input = relu(agg1), applied on read) ----
    k_linear<<<512, b256, 0, stream>>>(agg1, 1, Wq2, bq2, Wk2, bk2, Wv2, bv2, Ws2, bs2,
                                       q, kvh, agg2);
    k_edge<<<wgrid, b256, 0, stream>>>(pairP, off, q, (const uint4*)kvh, We2, agg2);

    // ---- pool + head (relu applied on read of agg2) ----
    k_final<<<NG, b256, 0, stream>>>(agg2, batch, Wl, bl, out);
}

// Round 7
// 237.808 us; speedup vs baseline: 5.4626x; 1.1052x over previous
//
#include <hip/hip_runtime.h>
#include <hip/hip_fp16.h>

#define NN 50000
#define NE 1250000
#define NG 256
#define NBKT 782          // ceil(NN/64) buckets of 64 nodes
#define TILE 4096         // edges per multisplit block
#define NTB 306           // ceil(NE/TILE)

#define QSCALE 0.18033688011112042f   // log2(e)/8
#define EXP2 __builtin_amdgcn_exp2f

// ---------- phase 1a: bucket histogram ----------
__global__ void k_bcount(const int* __restrict__ dst, int* __restrict__ bcnt) {
    __shared__ int cnt[NBKT];
    for (int i = threadIdx.x; i < NBKT; i += 256) cnt[i] = 0;
    __syncthreads();
    int e0 = blockIdx.x * TILE;
    #pragma unroll
    for (int j = 0; j < 16; j++) {
        int e = e0 + j * 256 + threadIdx.x;
        if (e < NE) atomicAdd(&cnt[dst[e] >> 6], 1);
    }
    __syncthreads();
    for (int i = threadIdx.x; i < NBKT; i += 256)
        if (cnt[i]) atomicAdd(&bcnt[i], cnt[i]);
}

// ---------- phase 1b: scan bucket counts -> bases; off sentinel ----------
__global__ void k_bscan(const int* __restrict__ bcnt, int* __restrict__ bstart,
                        int* __restrict__ gCursor, int* __restrict__ off) {
    __shared__ int s[256];
    int t = threadIdx.x;
    int c[4]; int sum = 0;
    #pragma unroll
    for (int j = 0; j < 4; j++) {
        int b = t * 4 + j;
        c[j] = (b < NBKT) ? bcnt[b] : 0;
        sum += c[j];
    }
    s[t] = sum;
    __syncthreads();
    for (int o = 1; o < 256; o <<= 1) {
        int tmp = (t >= o) ? s[t - o] : 0;
        __syncthreads();
        s[t] += tmp;
        __syncthreads();
    }
    int run = s[t] - sum;   // exclusive base for this thread's 4 buckets
    #pragma unroll
    for (int j = 0; j < 4; j++) {
        int b = t * 4 + j;
        if (b < NBKT) { bstart[b] = run; gCursor[b] = run; }
        run += c[j];
    }
    if (t == 0) off[NN] = NE;   // CSR sentinel
}

// ---------- phase 1c: multisplit scatter to coarse bucket regions ----------
// rec.x = src (16b) | (d&63)<<16 | bucket<<22
__global__ void k_bscatter(const int* __restrict__ src, const int* __restrict__ dst,
                           const float* __restrict__ ew, int* __restrict__ gCursor,
                           int2* __restrict__ bbuf) {
    __shared__ int cnt[NBKT];
    __shared__ int base[NBKT];
    for (int i = threadIdx.x; i < NBKT; i += 256) cnt[i] = 0;
    __syncthreads();
    int e0 = blockIdx.x * TILE;
    int2 rec[16];
    #pragma unroll
    for (int j = 0; j < 16; j++) {
        int e = e0 + j * 256 + threadIdx.x;
        if (e < NE) {
            int d = dst[e];
            int b = d >> 6;
            rec[j] = make_int2(src[e] | ((d & 63) << 16) | (b << 22), __float_as_int(ew[e]));
            atomicAdd(&cnt[b], 1);
        } else rec[j].x = -1;
    }
    __syncthreads();
    for (int i = threadIdx.x; i < NBKT; i += 256)
        base[i] = cnt[i] ? atomicAdd(&gCursor[i], cnt[i]) : 0;
    __syncthreads();
    #pragma unroll
    for (int j = 0; j < 16; j++) {
        if (rec[j].x != -1) {
            int b = ((unsigned)rec[j].x) >> 22;
            int pos = atomicAdd(&base[b], 1);
            bbuf[pos] = rec[j];
        }
    }
}

// ---------- phase 2: per-bucket sort into final CSR (packed 4B pairs); emits off ----------
__global__ void k_bsort(const int* __restrict__ bcnt, const int* __restrict__ bstart,
                        const int2* __restrict__ bbuf,
                        int* __restrict__ off, unsigned* __restrict__ pairP) {
    int b = blockIdx.x;
    int st = bstart[b], ce = bcnt[b];
    __shared__ int2 sbuf[4096];      // 32KB; avg bucket ~1600, P[>4096] ~ 0
    __shared__ int h[64];
    __shared__ int cur[64];
    if (threadIdx.x < 64) h[threadIdx.x] = 0;
    __syncthreads();
    bool fits = (ce <= 4096);
    for (int i = threadIdx.x; i < ce; i += 256) {
        int2 r = bbuf[st + i];
        if (fits) sbuf[i] = r;
        atomicAdd(&h[(r.x >> 16) & 63], 1);
    }
    __syncthreads();
    if (threadIdx.x < 64) {
        int v = h[threadIdx.x];
        int inc = v;
        #pragma unroll
        for (int o = 1; o < 64; o <<= 1) {
            int tmp = __shfl_up(inc, o);
            if (threadIdx.x >= o) inc += tmp;
        }
        int exc = st + inc - v;
        cur[threadIdx.x] = exc;
        int n = b * 64 + threadIdx.x;
        if (n < NN) off[n] = exc;
    }
    __syncthreads();
    for (int i = threadIdx.x; i < ce; i += 256) {
        int2 r = fits ? sbuf[i] : bbuf[st + i];
        int pos = atomicAdd(&cur[(r.x >> 16) & 63], 1);
        unsigned hw = (unsigned)__half_as_ushort(__float2half(__int_as_float(r.y)));
        pairP[pos] = (unsigned)(r.x & 0xFFFF) | (hw << 16);
    }
}

// ---------- fused node linear: wave = matrix (0=q,1=k,2=v,3=s), W column in regs ----------
// q written pre-scaled by log2(e)/8; kv row = [64 k-halfs][64 v-halfs]
// 4 independent accumulators (ILP); grid 1024 (16 waves/CU)
__global__ __launch_bounds__(256, 4)
void k_linear(const float* __restrict__ xin, int relu_in,
              const float* __restrict__ Wq, const float* __restrict__ bq,
              const float* __restrict__ Wk, const float* __restrict__ bk,
              const float* __restrict__ Wv, const float* __restrict__ bv,
              const float* __restrict__ Ws, const float* __restrict__ bs,
              float* __restrict__ q, __half* __restrict__ kvh,
              float* __restrict__ agg) {
    int tid = threadIdx.x;
    int mat = tid >> 6, feat = tid & 63;
    const float* W = mat == 0 ? Wq : mat == 1 ? Wk : mat == 2 ? Wv : Ws;
    const float* b = mat == 0 ? bq : mat == 1 ? bk : mat == 2 ? bv : bs;

    float wcol[64];
    #pragma unroll
    for (int kk = 0; kk < 64; kk++) wcol[kk] = W[kk * 64 + feat];
    float bias = b[feat];
    int kvoff = feat + (mat == 2 ? 64 : 0);

    __shared__ float sx[16 * 64];
    const float4* x4 = (const float4*)xin;

    for (int n0 = blockIdx.x * 16; n0 < NN; n0 += gridDim.x * 16) {
        __syncthreads();
        float4 xv = x4[n0 * 16 + tid];   // 256 threads x float4 = 16 nodes
        if (relu_in) {
            xv.x = fmaxf(xv.x, 0.f); xv.y = fmaxf(xv.y, 0.f);
            xv.z = fmaxf(xv.z, 0.f); xv.w = fmaxf(xv.w, 0.f);
        }
        ((float4*)sx)[tid] = xv;
        __syncthreads();
        for (int c = 0; c < 16; c++) {
            const float4* sxc = (const float4*)(sx + c * 64);
            float a0 = bias, a1 = 0.f, a2 = 0.f, a3 = 0.f;
            #pragma unroll
            for (int k4 = 0; k4 < 16; k4 += 4) {
                float4 v0 = sxc[k4 + 0], v1 = sxc[k4 + 1];
                float4 v2 = sxc[k4 + 2], v3 = sxc[k4 + 3];
                a0 = fmaf(v0.x, wcol[4 * k4 + 0], a0);
                a0 = fmaf(v0.y, wcol[4 * k4 + 1], a0);
                a0 = fmaf(v0.z, wcol[4 * k4 + 2], a0);
                a0 = fmaf(v0.w, wcol[4 * k4 + 3], a0);
                a1 = fmaf(v1.x, wcol[4 * k4 + 4], a1);
                a1 = fmaf(v1.y, wcol[4 * k4 + 5], a1);
                a1 = fmaf(v1.z, wcol[4 * k4 + 6], a1);
                a1 = fmaf(v1.w, wcol[4 * k4 + 7], a1);
                a2 = fmaf(v2.x, wcol[4 * k4 + 8], a2);
                a2 = fmaf(v2.y, wcol[4 * k4 + 9], a2);
                a2 = fmaf(v2.z, wcol[4 * k4 + 10], a2);
                a2 = fmaf(v2.w, wcol[4 * k4 + 11], a2);
                a3 = fmaf(v3.x, wcol[4 * k4 + 12], a3);
                a3 = fmaf(v3.y, wcol[4 * k4 + 13], a3);
                a3 = fmaf(v3.z, wcol[4 * k4 + 14], a3);
                a3 = fmaf(v3.w, wcol[4 * k4 + 15], a3);
            }
            float acc = (a0 + a1) + (a2 + a3);
            int nn = n0 + c;
            if (mat == 0)      q[nn * 64 + feat] = acc * QSCALE;
            else if (mat == 3) agg[nn * 64 + feat] = acc;
            else               kvh[nn * 128 + kvoff] = __float2half(acc);
        }
    }
}

// ---------- fused edge kernel: wave per dst node, 8-lane groups, no-max softmax ----------
// pipeline: pairs 2 iters ahead, kv 1 iter ahead (VGPR < 64 keeps 8 waves/SIMD)
__global__ void k_edge(const unsigned* __restrict__ pairP,
                       const int* __restrict__ off,
                       const float* __restrict__ q, const uint4* __restrict__ kv16,
                       const float* __restrict__ We, float* __restrict__ agg) {
    long gid = (long)blockIdx.x * 256 + threadIdx.x;
    int n = (int)(gid >> 6);
    if (n >= NN) return;
    int lane = threadIdx.x & 63;
    int g = lane >> 3, l = lane & 7;   // 8 groups x 8 lanes

    // per-lane 8 q feats (f32, pre-scaled), 8 We feats
    const float4* qp = (const float4*)(q + n * 64 + l * 8);
    float4 qa = qp[0], qb = qp[1];
    const float4* wp = (const float4*)(We + l * 8);
    float4 wa = wp[0], wb = wp[1];

    int st = off[n], dg = off[n + 1] - st;

    // per-node scalar qWe (scaled domain)
    float qwe = qa.x * wa.x + qa.y * wa.y + qa.z * wa.z + qa.w * wa.w
              + qb.x * wb.x + qb.y * wb.y + qb.z * wb.z + qb.w * wb.w;
    qwe += __shfl_xor(qwe, 1); qwe += __shfl_xor(qwe, 2); qwe += __shfl_xor(qwe, 4);

    float den = 0.f, sw = 0.f;
    float acc[8] = {0.f, 0.f, 0.f, 0.f, 0.f, 0.f, 0.f, 0.f};

    auto edge = [&](unsigned pr, uint4 kk, uint4 vv) {
        float w = __half2float(__ushort_as_half((unsigned short)(pr >> 16)));
        float2 k0 = __half22float2(*(const __half2*)&kk.x);
        float2 k1 = __half22float2(*(const __half2*)&kk.y);
        float2 k2 = __half22float2(*(const __half2*)&kk.z);
        float2 k3 = __half22float2(*(const __half2*)&kk.w);
        float t = qa.x * k0.x;
        t = fmaf(qa.y, k0.y, t); t = fmaf(qa.z, k1.x, t); t = fmaf(qa.w, k1.y, t);
        t = fmaf(qb.x, k2.x, t); t = fmaf(qb.y, k2.y, t);
        t = fmaf(qb.z, k3.x, t); t = fmaf(qb.w, k3.y, t);
        t += __shfl_xor(t, 1); t += __shfl_xor(t, 2); t += __shfl_xor(t, 4);
        t = fmaf(w, qwe, t);
        float p = EXP2(t);             // shift-invariant softmax: |t| << 127, no overflow
        den += p;
        sw = fmaf(p, w, sw);
        float2 v0 = __half22float2(*(const __half2*)&vv.x);
        float2 v1 = __half22float2(*(const __half2*)&vv.y);
        float2 v2 = __half22float2(*(const __half2*)&vv.z);
        float2 v3 = __half22float2(*(const __half2*)&vv.w);
        acc[0] = fmaf(p, v0.x, acc[0]); acc[1] = fmaf(p, v0.y, acc[1]);
        acc[2] = fmaf(p, v1.x, acc[2]); acc[3] = fmaf(p, v1.y, acc[3]);
        acc[4] = fmaf(p, v2.x, acc[4]); acc[5] = fmaf(p, v2.y, acc[5]);
        acc[6] = fmaf(p, v3.x, acc[6]); acc[7] = fmaf(p, v3.y, acc[7]);
    };

    int nfull = dg >> 3;
    if (nfull > 0) {
        unsigned prA = pairP[st + g];
        unsigned prB = (nfull > 1) ? pairP[st + 8 + g] : 0u;
        unsigned rowA = prA & 0xFFFFu;
        uint4 kkA = kv16[rowA * 16 + l];
        uint4 vvA = kv16[rowA * 16 + 8 + l];
        for (int i = 0; i + 1 < nfull; i++) {
            unsigned prC = (i + 2 < nfull) ? pairP[st + (i + 2) * 8 + g] : 0u;
            unsigned rowB = prB & 0xFFFFu;
            uint4 kkB = kv16[rowB * 16 + l];
            uint4 vvB = kv16[rowB * 16 + 8 + l];
            edge(prA, kkA, vvA);
            prA = prB; kkA = kkB; vvA = vvB; prB = prC;
        }
        edge(prA, kkA, vvA);
    }
    int tl = nfull * 8 + g;
    if (tl < dg) {
        unsigned pr = pairP[st + tl];
        unsigned row = pr & 0xFFFFu;
        uint4 kk = kv16[row * 16 + l];
        uint4 vv = kv16[row * 16 + 8 + l];
        edge(pr, kk, vv);
    }

    // merge the 8 group states (pure adds)
    #pragma unroll
    for (int o = 8; o <= 32; o <<= 1) {
        den += __shfl_xor(den, o);
        sw  += __shfl_xor(sw, o);
        #pragma unroll
        for (int j = 0; j < 8; j++) acc[j] += __shfl_xor(acc[j], o);
    }

    if (g == 0) {
        float inv = 1.f / fmaxf(den, 1e-16f);
        float swi = sw * inv;
        float4* a4 = (float4*)(agg + n * 64 + l * 8);
        float4 a0 = a4[0], a1 = a4[1];
        a0.x = fmaf(acc[0], inv, fmaf(swi, wa.x, a0.x));
        a0.y = fmaf(acc[1], inv, fmaf(swi, wa.y, a0.y));
        a0.z = fmaf(acc[2], inv, fmaf(swi, wa.z, a0.z));
        a0.w = fmaf(acc[3], inv, fmaf(swi, wa.w, a0.w));
        a1.x = fmaf(acc[4], inv, fmaf(swi, wb.x, a1.x));
        a1.y = fmaf(acc[5], inv, fmaf(swi, wb.y, a1.y));
        a1.z = fmaf(acc[6], inv, fmaf(swi, wb.z, a1.z));
        a1.w = fmaf(acc[7], inv, fmaf(swi, wb.w, a1.w));
        a4[0] = a0; a4[1] = a1;
    }
}

// ---------- pool + head: block per graph, batch is sorted ----------
__global__ void k_final(const float* __restrict__ h, const int* __restrict__ batch,
                        const float* __restrict__ Wl, const float* __restrict__ bl,
                        float* __restrict__ out) {
    int g = blockIdx.x;
    int tid = threadIdx.x;
    int lo = 0, hi = NN;
    while (lo < hi) { int mid = (lo + hi) >> 1; if (batch[mid] < g) lo = mid + 1; else hi = mid; }
    int s0 = lo;
    hi = NN;
    while (lo < hi) { int mid = (lo + hi) >> 1; if (batch[mid] < g + 1) lo = mid + 1; else hi = mid; }
    int s1 = lo;

    int sub = tid >> 6, lane = tid & 63;
    float a = 0.f;
    for (int n = s0 + sub; n < s1; n += 4) a += fmaxf(h[n * 64 + lane], 0.f);
    __shared__ float sred[4][64];
    sred[sub][lane] = a;
    __syncthreads();
    if (tid < 64) {
        float p = (sred[0][tid] + sred[1][tid] + sred[2][tid] + sred[3][tid])
                  / fmaxf((float)(s1 - s0), 1.f);
        float a0 = p * Wl[tid * 2 + 0];
        float a1 = p * Wl[tid * 2 + 1];
        #pragma unroll
        for (int o = 1; o < 64; o <<= 1) { a0 += __shfl_xor(a0, o); a1 += __shfl_xor(a1, o); }
        if (tid == 0) { out[g * 2 + 0] = a0 + bl[0]; out[g * 2 + 1] = a1 + bl[1]; }
    }
}

extern "C" void kernel_launch(void* const* d_in, const int* in_sizes, int n_in,
                              void* d_out, int out_size, void* d_ws, size_t ws_size,
                              hipStream_t stream) {
    const float* x    = (const float*)d_in[0];
    const int*   ei   = (const int*)d_in[1];
    const float* ew   = (const float*)d_in[2];
    const int*   batch= (const int*)d_in[3];
    const float *Wq1 = (const float*)d_in[4],  *bq1 = (const float*)d_in[5],
                *Wk1 = (const float*)d_in[6],  *bk1 = (const float*)d_in[7],
                *Wv1 = (const float*)d_in[8],  *bv1 = (const float*)d_in[9],
                *We1 = (const float*)d_in[10], *Ws1 = (const float*)d_in[11],
                *bs1 = (const float*)d_in[12],
                *Wq2 = (const float*)d_in[13], *bq2 = (const float*)d_in[14],
                *Wk2 = (const float*)d_in[15], *bk2 = (const float*)d_in[16],
                *Wv2 = (const float*)d_in[17], *bv2 = (const float*)d_in[18],
                *We2 = (const float*)d_in[19], *Ws2 = (const float*)d_in[20],
                *bs2 = (const float*)d_in[21],
                *Wl  = (const float*)d_in[22], *bl  = (const float*)d_in[23];
    const int* src = ei;        // edge_index[0]
    const int* dst = ei + NE;   // edge_index[1]
    float* out = (float*)d_out;

    float* p = (float*)d_ws;
    float* q    = p; p += (size_t)NN * 64;
    float* agg1 = p; p += (size_t)NN * 64;
    float* agg2 = p; p += (size_t)NN * 64;
    __half* kvh = (__half*)p; p += (size_t)NN * 64;   // NN*128 halfs
    int2* bbuf  = (int2*)p;  p += (size_t)NE * 2;
    unsigned* pairP = (unsigned*)p; p += (size_t)NE;
    int* ip = (int*)p;
    int* bcnt    = ip; ip += NBKT;
    int* bstart  = ip; ip += NBKT;
    int* gCursor = ip; ip += NBKT;
    int* off     = ip; ip += NN + 1;

    dim3 b256(256);
    int wgrid = (int)(((long)NN * 64 + 255) / 256);     // wave per node: 12500

    // ---- CSR build via two-level multisplit (shared by both layers) ----
    hipMemsetAsync(bcnt, 0, NBKT * sizeof(int), stream);
    k_bcount<<<NTB, b256, 0, stream>>>(dst, bcnt);
    k_bscan<<<1, b256, 0, stream>>>(bcnt, bstart, gCursor, off);
    k_bscatter<<<NTB, b256, 0, stream>>>(src, dst, ew, gCursor, bbuf);
    k_bsort<<<NBKT, b256, 0, stream>>>(bcnt, bstart, bbuf, off, pairP);

    // ---- layer 1 ----
    k_linear<<<1024, b256, 0, stream>>>(x, 0, Wq1, bq1, Wk1, bk1, Wv1, bv1, Ws1, bs1,
                                        q, kvh, agg1);
    k_edge<<<wgrid, b256, 0, stream>>>(pairP, off, q, (const uint4*)kvh, We1, agg1);

    // ---- layer 2 (input = relu(agg1), applied on read) ----
    k_linear<<<1024, b256, 0, stream>>>(agg1, 1, Wq2, bq2, Wk2, bk2, Wv2, bv2, Ws2, bs2,
                                        q, kvh, agg2);
    k_edge<<<wgrid, b256, 0, stream>>>(pairP, off, q, (const uint4*)kvh, We2, agg2);

    // ---- pool + head (relu applied on read of agg2) ----
    k_final<<<NG, b256, 0, stream>>>(agg2, batch, Wl, bl, out);
}